// Round 16
// baseline (73.695 us; speedup 1.0000x reference)
//
#include <hip/hip_runtime.h>
#include <hip/hip_bf16.h>
#include <stdint.h>

typedef unsigned short u16;
typedef unsigned int u32;
typedef __attribute__((ext_vector_type(8))) short short8;
typedef __attribute__((ext_vector_type(4))) short short4_t;
typedef __attribute__((ext_vector_type(4))) float f32x4;
typedef __attribute__((ext_vector_type(16))) float f32x16;

#define MFMA16(A,B,C) __builtin_amdgcn_mfma_f32_16x16x32_bf16((A),(B),(C),0,0,0)
#define MFMA32(A,B,C) __builtin_amdgcn_mfma_f32_32x32x16_bf16((A),(B),(C),0,0,0)
#define L2E 1.4426950408889634f

__device__ __forceinline__ u16 f2bf(float f) {
  u32 x = __float_as_uint(f);
  u32 r = x + 0x7fffu + ((x >> 16) & 1u);
  return (u16)(r >> 16);
}
__device__ __forceinline__ float bf2f(short v) {
  return __uint_as_float((u32)(u16)v << 16);
}
__device__ __forceinline__ u32 pack_bf2(float a, float b) {
  __hip_bfloat162 h = __float22bfloat162_rn(make_float2(a, b));
  u32 u; __builtin_memcpy(&u, &h, 4); return u;
}
__device__ __forceinline__ short8 mk_frag(u32 w0, u32 w1, u32 w2, u32 w3) {
  union { u32 u[4]; short8 s; } cv;
  cv.u[0] = w0; cv.u[1] = w1; cv.u[2] = w2; cv.u[3] = w3;
  return cv.s;
}

#if __has_builtin(__builtin_amdgcn_permlane32_swap)
__device__ __forceinline__ float half_sum(float x) {
  u32 xu = __float_as_uint(x);
  auto a = __builtin_amdgcn_permlane32_swap(xu, xu, false, false);
  return __uint_as_float(a[0]) + __uint_as_float(a[1]);
}
#else
__device__ __forceinline__ float half_sum(float x) {
  return x + __shfl_xor(x, 32, 64);
}
#endif

// weight-tile swizzle: separates row stripes AND 32-col groups so transpose
// writes hit distinct bank quartets.  Bits 4..7, bijective per row.
__device__ __forceinline__ int wswz(int n) {
  return ((n & 7) ^ ((n >> 5) & 3)) << 4;
}

// In-block transpose of a 128x128 f32 matrix into a swizzled bf16 LDS tile.
__device__ __forceinline__ void transpose_to_lds(const float* __restrict__ Sg,
                                                 char* btc, int tid)
{
  const int kr = (tid >> 2) * 2;
  const int nc = (tid & 3) * 32;
  const float* r0 = Sg + kr * 128 + nc;
  const float* r1 = r0 + 128;
  #pragma unroll
  for (int j4 = 0; j4 < 8; ++j4) {
    float4 a = *reinterpret_cast<const float4*>(r0 + j4 * 4);
    float4 b = *reinterpret_cast<const float4*>(r1 + j4 * 4);
    #pragma unroll
    for (int e = 0; e < 4; ++e) {
      int n = nc + j4 * 4 + e;
      *reinterpret_cast<u32*>(btc + ((n * 256 + kr * 2) ^ wswz(n))) =
          pack_bf2((&a.x)[e], (&b.x)[e]);
    }
  }
}

// ---------------- kernel 1: 5 projections, packed layouts -----------------
__global__ __launch_bounds__(256) void kproj(const float* __restrict__ head,
    const float* __restrict__ tail,
    const float* __restrict__ R_q, const float* __restrict__ R_k,
    const float* __restrict__ R_v, const float* __restrict__ F_q,
    const float* __restrict__ F_k, const float* __restrict__ F_v,
    const float* __restrict__ conv_w, const float* __restrict__ conv_b,
    const float* __restrict__ bn_w, const float* __restrict__ bn_b,
    const float* __restrict__ bn_mean, const float* __restrict__ bn_var,
    u16* __restrict__ qT, u16* __restrict__ KQ,
    u16* __restrict__ Vc, const int* __restrict__ flagp)
{
  __shared__ __align__(16) char bt[32768];
  __shared__ u16 lds_t[128][34];
  __shared__ float s_alpha[128];
  const int flag = *flagp;
  const float* X1 = flag ? head : tail;
  const float* X2 = flag ? tail : head;
  const int bh = blockIdx.x, g = blockIdx.y;
  const int b = bh >> 5, h = bh & 31;
  const float* src = (g < 3) ? X1 : X2;
  const int tid = threadIdx.x, lane = tid & 63, wid = tid >> 6;
  const int lrow = lane & 15, lg = lane >> 4;
  const int rt = wid & 1, cbase = (wid >> 1) * 64;

  {
    const float* s1[5] = {R_q, R_k, R_v, F_k, F_v};
    const float* s0[5] = {F_q, F_k, F_v, R_k, R_v};
    transpose_to_lds(flag ? s1[g] : s0[g], bt, tid);
  }

  if (g == 3) {
    if (tid < 128) {
      int w = tid;
      const float* hp = head + ((size_t)b * 1024 + h) * 128 + w;
      const float* tp = tail + ((size_t)b * 1024 + h) * 128 + w;
      float a0 = 0.f, a1 = 0.f;
      for (int c = 0; c < 32; ++c) {
        float xh = hp[c * 4096];
        float xt = tp[c * 4096];
        a0 += xh * conv_w[c]      + xt * conv_w[32 + c];
        a1 += xh * conv_w[64 + c] + xt * conv_w[96 + c];
      }
      const float eps = 1e-5f;
      a0 += conv_b[0]; a1 += conv_b[1];
      a0 = (a0 - bn_mean[0]) * (bn_w[0] * rsqrtf(bn_var[0] + eps)) + bn_b[0];
      a1 = (a1 - bn_mean[1]) * (bn_w[1] * rsqrtf(bn_var[1] + eps)) + bn_b[1];
      a0 = fmaxf(a0, 0.f); a1 = fmaxf(a1, 0.f);
      float asel = flag ? a0 : a1, aoth = flag ? a1 : a0;
      s_alpha[w] = 1.f / (1.f + __expf(aoth - asel));
    }
  }
  __syncthreads();

  f32x4 acc[4] = {};
  const float* Arow = src + (((size_t)b * 32 + rt * 16 + lrow) * 32 + h) * 128;
  #pragma unroll
  for (int k0 = 0; k0 < 128; k0 += 32) {
    const float* ap = Arow + k0 + lg * 8;
    float4 f0 = *reinterpret_cast<const float4*>(ap);
    float4 f1 = *reinterpret_cast<const float4*>(ap + 4);
    short8 af = mk_frag(pack_bf2(f0.x, f0.y), pack_bf2(f0.z, f0.w),
                        pack_bf2(f1.x, f1.y), pack_bf2(f1.z, f1.w));
    #pragma unroll
    for (int cc = 0; cc < 4; ++cc) {
      int n = cbase + cc * 16 + lrow;
      short8 bf = *reinterpret_cast<const short8*>(
          bt + ((n * 256 + k0 * 2 + lg * 16) ^ wswz(n)));
      acc[cc] = MFMA16(af, bf, acc[cc]);
    }
  }
  #pragma unroll
  for (int cc = 0; cc < 4; ++cc) {
    int n = cbase + cc * 16 + lrow;
    float asc = (g == 1) ? L2E : 1.f;
    if (g == 3) asc = s_alpha[n] * L2E;
    #pragma unroll
    for (int rr = 0; rr < 4; ++rr) {
      int c = rt * 16 + lg * 4 + rr;
      lds_t[n][c] = f2bf(acc[cc][rr] * asc);
    }
  }
  __syncthreads();
  if (g == 0) {
    int c = tid >> 3, w0 = (tid & 7) * 16;
    int tw[8];
    #pragma unroll
    for (int i2 = 0; i2 < 8; ++i2)
      tw[i2] = (int)lds_t[w0 + 2 * i2][c] | ((int)lds_t[w0 + 2 * i2 + 1][c] << 16);
    int4* dst = reinterpret_cast<int4*>(qT + ((size_t)b * 32 + c) * 4096 + h * 128 + w0);
    dst[0] = make_int4(tw[0], tw[1], tw[2], tw[3]);
    dst[1] = make_int4(tw[4], tw[5], tw[6], tw[7]);
  } else if (tid < 128) {
    int w = tid;
    int tw[16];
    #pragma unroll
    for (int i2 = 0; i2 < 16; ++i2)
      tw[i2] = (int)lds_t[w][2 * i2] | ((int)lds_t[w][2 * i2 + 1] << 16);
    u16* base = (g == 2 || g == 4) ? Vc : KQ;
    int coff = (g >= 3) ? 32 : 0;
    int4* dst = reinterpret_cast<int4*>(base + ((size_t)b * 4096 + h * 128 + w) * 64 + coff);
    dst[0] = make_int4(tw[0],  tw[1],  tw[2],  tw[3]);
    dst[1] = make_int4(tw[4],  tw[5],  tw[6],  tw[7]);
    dst[2] = make_int4(tw[8],  tw[9],  tw[10], tw[11]);
    dst[3] = make_int4(tw[12], tw[13], tw[14], tw[15]);
  }
}

// ---------------- kernel 2: flash attention (R12, proven) -----------------
__global__ __launch_bounds__(256, 4) void kattn(const u16* __restrict__ qT,
    const u16* __restrict__ KQ, const u16* __restrict__ Vc,
    u16* __restrict__ pO, float* __restrict__ pl)
{
  __shared__ __align__(16) char lds_v[2][8192];
  __shared__ __align__(16) char lds_q[2][4096];
  const int b = blockIdx.y;
  const int i0 = blockIdx.x * 128;
  const int sp = blockIdx.z;
  const int jbase = sp * 512;
  const int tid = threadIdx.x, lane = tid & 63, wid = tid >> 6;
  const int l31 = lane & 31, h = lane >> 5;
  const int iw = i0 + wid * 32;

  const u16* KQb = KQ + (size_t)b * 4096 * 64;
  const u16* Vb  = Vc + (size_t)b * 4096 * 64;
  const u16* qTb = qT + (size_t)b * 32 * 4096;

  short8 bkq[4];
  #pragma unroll
  for (int c = 0; c < 4; ++c)
    bkq[c] = *reinterpret_cast<const short8*>(
        KQb + (size_t)(iw + l31) * 64 + c * 16 + h * 8);

  const int sr = tid >> 3, sx = (tid & 7) * 16;
  const int pr0 = (sr & ~12) | ((sr & 4) << 1) | ((sr & 8) >> 1);

  #pragma unroll
  for (int q = 0; q < 2; ++q) {
    int r = sr + q * 32, gr = pr0 + q * 32;
    int4 v = *reinterpret_cast<const int4*>(
        reinterpret_cast<const char*>(Vb + (size_t)(jbase + gr) * 64) + sx);
    *reinterpret_cast<int4*>(lds_v[0] + r * 128 + (sx ^ ((r & 7) << 4))) = v;
  }
  {
    int4 qv = *reinterpret_cast<const int4*>(
        qTb + (size_t)sr * 4096 + jbase + (tid & 7) * 8);
    *reinterpret_cast<int4*>(lds_q[0] + sr * 128 + (sx ^ ((sr & 7) << 4))) = qv;
  }
  __syncthreads();

  float l_run = 0.f;
  f32x16 accO = {};
  int4 stgV[2], stgQ;

  for (int t = 0; t < 8; ++t) {
    const int buf = t & 1;
    if (t < 7) {
      const u16* Vn = Vb + (size_t)(jbase + (t + 1) * 64) * 64;
      #pragma unroll
      for (int q = 0; q < 2; ++q) {
        int gr = pr0 + q * 32;
        stgV[q] = *reinterpret_cast<const int4*>(
            reinterpret_cast<const char*>(Vn + (size_t)gr * 64) + sx);
      }
      stgQ = *reinterpret_cast<const int4*>(
          qTb + (size_t)sr * 4096 + jbase + (t + 1) * 64 + (tid & 7) * 8);
    }
    f32x16 st[2];
    st[0] = f32x16{}; st[1] = f32x16{};
    __builtin_amdgcn_s_setprio(1);
    #pragma unroll
    for (int jt = 0; jt < 2; ++jt) {
      int vr = jt * 32 + l31;
      #pragma unroll
      for (int c = 0; c < 4; ++c) {
        short8 av = *reinterpret_cast<const short8*>(
            lds_v[buf] + vr * 128 + ((c * 32 + h * 16) ^ ((vr & 7) << 4)));
        st[jt] = MFMA32(av, bkq[c], st[jt]);
      }
    }
    __builtin_amdgcn_s_setprio(0);
    short8 aq[4];
    #pragma unroll
    for (int cc = 0; cc < 4; ++cc)
      aq[cc] = *reinterpret_cast<const short8*>(
          lds_q[buf] + l31 * 128 + ((cc * 32 + h * 16) ^ ((l31 & 7) << 4)));
    #pragma unroll
    for (int jt = 0; jt < 2; ++jt)
      #pragma unroll
      for (int r = 0; r < 16; ++r) {
        float p = exp2f(st[jt][r]);
        st[jt][r] = p;
        l_run += p;
      }
    __builtin_amdgcn_s_setprio(1);
    #pragma unroll
    for (int cc = 0; cc < 4; ++cc) {
      const int jt = cc >> 1, p8 = (cc & 1) * 8;
      short8 bp = mk_frag(pack_bf2(st[jt][p8 + 0], st[jt][p8 + 1]),
                          pack_bf2(st[jt][p8 + 2], st[jt][p8 + 3]),
                          pack_bf2(st[jt][p8 + 4], st[jt][p8 + 5]),
                          pack_bf2(st[jt][p8 + 6], st[jt][p8 + 7]));
      accO = MFMA32(aq[cc], bp, accO);
    }
    __builtin_amdgcn_s_setprio(0);

    if (t < 7) {
      #pragma unroll
      for (int q = 0; q < 2; ++q) {
        int r = sr + q * 32;
        *reinterpret_cast<int4*>(lds_v[buf ^ 1] + r * 128 + (sx ^ ((r & 7) << 4))) = stgV[q];
      }
      *reinterpret_cast<int4*>(lds_q[buf ^ 1] + sr * 128 + (sx ^ ((sr & 7) << 4))) = stgQ;
      __syncthreads();
    }
  }

  const int i = iw + l31;
  u16* pOb = pO + (size_t)((b * 8 + sp) * 32) * 4096;
  #pragma unroll
  for (int r = 0; r < 16; ++r) {
    int c = (r & 3) + 8 * (r >> 2) + 4 * h;
    pOb[(size_t)c * 4096 + i] = f2bf(accO[r]);
  }
  float l = half_sum(l_run);
  if (h == 0) pl[(b * 8 + sp) * 4096 + i] = l;
}

// ---------------- kernel 3: sum partials + final mix + residual -----------
__global__ __launch_bounds__(256) void kout(const u16* __restrict__ pO,
    const float* __restrict__ pl,
    const float* __restrict__ R_W, const float* __restrict__ F_W,
    const float* __restrict__ head, const float* __restrict__ tail,
    const int* __restrict__ flagp, float* __restrict__ out)
{
  __shared__ __align__(16) char btW[32768];
  __shared__ u16 ylds[16][136];
  const int flag = *flagp;
  const float* X1 = flag ? head : tail;
  const int tid = threadIdx.x;
  const int b = blockIdx.x >> 6, c = (blockIdx.x >> 1) & 31, hh = blockIdx.x & 1;
  const int rbase = b * 1024 + c * 32 + hh * 16;
  const int ioff = hh * 2048 + tid * 8;

  transpose_to_lds(flag ? R_W : F_W, btW, tid);

  #pragma unroll
  for (int iq = 0; iq < 2; ++iq) {
    float4 L4 = {0.f, 0.f, 0.f, 0.f}, y4 = {0.f, 0.f, 0.f, 0.f};
    #pragma unroll
    for (int sp = 0; sp < 8; ++sp) {
      float4 l4 = *reinterpret_cast<const float4*>(
          pl + (size_t)((b * 8 + sp) * 4096) + ioff + iq * 4);
      L4.x += l4.x; L4.y += l4.y; L4.z += l4.z; L4.w += l4.w;
      short4_t o4 = *reinterpret_cast<const short4_t*>(
          pO + (size_t)(((b * 8 + sp) * 32 + c)) * 4096 + ioff + iq * 4);
      y4.x += bf2f(o4[0]); y4.y += bf2f(o4[1]);
      y4.z += bf2f(o4[2]); y4.w += bf2f(o4[3]);
    }
    y4.x /= L4.x; y4.y /= L4.y; y4.z /= L4.z; y4.w /= L4.w;
    uint2 pk2;
    pk2.x = pack_bf2(y4.x, y4.y);
    pk2.y = pack_bf2(y4.z, y4.w);
    *reinterpret_cast<uint2*>(&ylds[tid >> 4][(tid & 15) * 8 + iq * 4]) = pk2;
  }
  __syncthreads();

  const int lane = tid & 63, wid = tid >> 6;
  const int lrow = lane & 15, lg = lane >> 4;
  const int cg = wid * 32;
  f32x4 acc[2] = {};
  #pragma unroll
  for (int k0 = 0; k0 < 128; k0 += 32) {
    short8 af = *reinterpret_cast<const short8*>(&ylds[lrow][k0 + lg * 8]);
    #pragma unroll
    for (int cc = 0; cc < 2; ++cc) {
      int n = cg + cc * 16 + lrow;
      short8 bf = *reinterpret_cast<const short8*>(
          btW + ((n * 256 + k0 * 2 + lg * 16) ^ wswz(n)));
      acc[cc] = MFMA16(af, bf, acc[cc]);
    }
  }
  #pragma unroll
  for (int cc = 0; cc < 2; ++cc)
    #pragma unroll
    for (int rr = 0; rr < 4; ++rr) {
      int row = rbase + lg * 4 + rr;
      int col = cg + cc * 16 + lrow;
      size_t idx = (size_t)row * 128 + col;
      out[idx] = acc[cc][rr] + X1[idx];
    }
}

// ---------------- launch ---------------------------------------------------
extern "C" void kernel_launch(void* const* d_in, const int* in_sizes, int n_in,
                              void* d_out, int out_size, void* d_ws, size_t ws_size,
                              hipStream_t stream)
{
  const float* head    = (const float*)d_in[0];
  const float* tail    = (const float*)d_in[1];
  const float* R_q     = (const float*)d_in[2];
  const float* R_k     = (const float*)d_in[3];
  const float* R_v     = (const float*)d_in[4];
  const float* R_W     = (const float*)d_in[5];
  const float* F_q     = (const float*)d_in[6];
  const float* F_k     = (const float*)d_in[7];
  const float* F_v     = (const float*)d_in[8];
  const float* F_W     = (const float*)d_in[9];
  const float* conv_w  = (const float*)d_in[10];
  const float* conv_b  = (const float*)d_in[11];
  const float* bn_w    = (const float*)d_in[12];
  const float* bn_b    = (const float*)d_in[13];
  const float* bn_mean = (const float*)d_in[14];
  const float* bn_var  = (const float*)d_in[15];
  const int*   flagp   = (const int*)d_in[16];
  float* out = (float*)d_out;

  char* ws = (char*)d_ws;
  u16*   qT   = (u16*)(ws + 262144);
  u16*   KQ   = (u16*)(ws + 1310720);
  u16*   Vc   = (u16*)(ws + 3407872);
  u16*   pO   = (u16*)(ws + 6553600);
  float* pl   = (float*)(ws + 14942208);

  // MEASUREMENT: kproj and kout launched twice (both idempotent).
  // dur - 54.5 = kproj + kout + 2 boundaries.
  kproj <<<dim3(128, 5), 256, 0, stream>>>(head, tail, R_q, R_k, R_v,
                                           F_q, F_k, F_v, conv_w, conv_b,
                                           bn_w, bn_b, bn_mean, bn_var,
                                           qT, KQ, Vc, flagp);
  kproj <<<dim3(128, 5), 256, 0, stream>>>(head, tail, R_q, R_k, R_v,
                                           F_q, F_k, F_v, conv_w, conv_b,
                                           bn_w, bn_b, bn_mean, bn_var,
                                           qT, KQ, Vc, flagp);
  kattn <<<dim3(32, 4, 8), 256, 0, stream>>>(qT, KQ, Vc, pO, pl);
  kout  <<<256, 256, 0, stream>>>(pO, pl, R_W, F_W, head, tail, flagp, out);
  kout  <<<256, 256, 0, stream>>>(pO, pl, R_W, F_W, head, tail, flagp, out);
}

// Round 17
// 57.200 us; speedup vs baseline: 1.2884x; 1.2884x over previous
//
#include <hip/hip_runtime.h>
#include <hip/hip_bf16.h>
#include <stdint.h>

typedef unsigned short u16;
typedef unsigned int u32;
typedef __attribute__((ext_vector_type(8))) short short8;
typedef __attribute__((ext_vector_type(4))) short short4_t;
typedef __attribute__((ext_vector_type(4))) float f32x4;
typedef __attribute__((ext_vector_type(16))) float f32x16;

#define MFMA16(A,B,C) __builtin_amdgcn_mfma_f32_16x16x32_bf16((A),(B),(C),0,0,0)
#define MFMA32(A,B,C) __builtin_amdgcn_mfma_f32_32x32x16_bf16((A),(B),(C),0,0,0)
#define L2E 1.4426950408889634f

__device__ __forceinline__ u16 f2bf(float f) {
  u32 x = __float_as_uint(f);
  u32 r = x + 0x7fffu + ((x >> 16) & 1u);
  return (u16)(r >> 16);
}
__device__ __forceinline__ float bf2f(short v) {
  return __uint_as_float((u32)(u16)v << 16);
}
__device__ __forceinline__ u32 pack_bf2(float a, float b) {
  __hip_bfloat162 h = __float22bfloat162_rn(make_float2(a, b));
  u32 u; __builtin_memcpy(&u, &h, 4); return u;
}
__device__ __forceinline__ short8 mk_frag(u32 w0, u32 w1, u32 w2, u32 w3) {
  union { u32 u[4]; short8 s; } cv;
  cv.u[0] = w0; cv.u[1] = w1; cv.u[2] = w2; cv.u[3] = w3;
  return cv.s;
}

#if __has_builtin(__builtin_amdgcn_permlane32_swap)
__device__ __forceinline__ float half_sum(float x) {
  u32 xu = __float_as_uint(x);
  auto a = __builtin_amdgcn_permlane32_swap(xu, xu, false, false);
  return __uint_as_float(a[0]) + __uint_as_float(a[1]);
}
#else
__device__ __forceinline__ float half_sum(float x) {
  return x + __shfl_xor(x, 32, 64);
}
#endif

// weight-tile swizzle: separates row stripes AND 32-col groups so transpose
// writes hit distinct bank quartets.  Bits 4..7, bijective per row.
__device__ __forceinline__ int wswz(int n) {
  return ((n & 7) ^ ((n >> 5) & 3)) << 4;
}

// In-block transpose of a 128x128 f32 matrix into a swizzled bf16 LDS tile.
__device__ __forceinline__ void transpose_to_lds(const float* __restrict__ Sg,
                                                 char* btc, int tid)
{
  const int kr = (tid >> 2) * 2;
  const int nc = (tid & 3) * 32;
  const float* r0 = Sg + kr * 128 + nc;
  const float* r1 = r0 + 128;
  #pragma unroll
  for (int j4 = 0; j4 < 8; ++j4) {
    float4 a = *reinterpret_cast<const float4*>(r0 + j4 * 4);
    float4 b = *reinterpret_cast<const float4*>(r1 + j4 * 4);
    #pragma unroll
    for (int e = 0; e < 4; ++e) {
      int n = nc + j4 * 4 + e;
      *reinterpret_cast<u32*>(btc + ((n * 256 + kr * 2) ^ wswz(n))) =
          pack_bf2((&a.x)[e], (&b.x)[e]);
    }
  }
}

// ---------------- kernel 1: 5 projections, packed layouts -----------------
__global__ __launch_bounds__(256) void kproj(const float* __restrict__ head,
    const float* __restrict__ tail,
    const float* __restrict__ R_q, const float* __restrict__ R_k,
    const float* __restrict__ R_v, const float* __restrict__ F_q,
    const float* __restrict__ F_k, const float* __restrict__ F_v,
    const float* __restrict__ conv_w, const float* __restrict__ conv_b,
    const float* __restrict__ bn_w, const float* __restrict__ bn_b,
    const float* __restrict__ bn_mean, const float* __restrict__ bn_var,
    u16* __restrict__ qT, u16* __restrict__ KQ,
    u16* __restrict__ Vc, const int* __restrict__ flagp)
{
  __shared__ __align__(16) char bt[32768];
  __shared__ u16 lds_t[128][34];
  __shared__ float s_alpha[128];
  const int flag = *flagp;
  const float* X1 = flag ? head : tail;
  const float* X2 = flag ? tail : head;
  const int bh = blockIdx.x, g = blockIdx.y;
  const int b = bh >> 5, h = bh & 31;
  const float* src = (g < 3) ? X1 : X2;
  const int tid = threadIdx.x, lane = tid & 63, wid = tid >> 6;
  const int lrow = lane & 15, lg = lane >> 4;
  const int rt = wid & 1, cbase = (wid >> 1) * 64;

  {
    const float* s1[5] = {R_q, R_k, R_v, F_k, F_v};
    const float* s0[5] = {F_q, F_k, F_v, R_k, R_v};
    transpose_to_lds(flag ? s1[g] : s0[g], bt, tid);
  }

  if (g == 3) {
    if (tid < 128) {
      int w = tid;
      const float* hp = head + ((size_t)b * 1024 + h) * 128 + w;
      const float* tp = tail + ((size_t)b * 1024 + h) * 128 + w;
      float a0 = 0.f, a1 = 0.f;
      for (int c = 0; c < 32; ++c) {
        float xh = hp[c * 4096];
        float xt = tp[c * 4096];
        a0 += xh * conv_w[c]      + xt * conv_w[32 + c];
        a1 += xh * conv_w[64 + c] + xt * conv_w[96 + c];
      }
      const float eps = 1e-5f;
      a0 += conv_b[0]; a1 += conv_b[1];
      a0 = (a0 - bn_mean[0]) * (bn_w[0] * rsqrtf(bn_var[0] + eps)) + bn_b[0];
      a1 = (a1 - bn_mean[1]) * (bn_w[1] * rsqrtf(bn_var[1] + eps)) + bn_b[1];
      a0 = fmaxf(a0, 0.f); a1 = fmaxf(a1, 0.f);
      float asel = flag ? a0 : a1, aoth = flag ? a1 : a0;
      s_alpha[w] = 1.f / (1.f + __expf(aoth - asel));
    }
  }
  __syncthreads();

  f32x4 acc[4] = {};
  const float* Arow = src + (((size_t)b * 32 + rt * 16 + lrow) * 32 + h) * 128;
  #pragma unroll
  for (int k0 = 0; k0 < 128; k0 += 32) {
    const float* ap = Arow + k0 + lg * 8;
    float4 f0 = *reinterpret_cast<const float4*>(ap);
    float4 f1 = *reinterpret_cast<const float4*>(ap + 4);
    short8 af = mk_frag(pack_bf2(f0.x, f0.y), pack_bf2(f0.z, f0.w),
                        pack_bf2(f1.x, f1.y), pack_bf2(f1.z, f1.w));
    #pragma unroll
    for (int cc = 0; cc < 4; ++cc) {
      int n = cbase + cc * 16 + lrow;
      short8 bf = *reinterpret_cast<const short8*>(
          bt + ((n * 256 + k0 * 2 + lg * 16) ^ wswz(n)));
      acc[cc] = MFMA16(af, bf, acc[cc]);
    }
  }
  #pragma unroll
  for (int cc = 0; cc < 4; ++cc) {
    int n = cbase + cc * 16 + lrow;
    float asc = (g == 1) ? L2E : 1.f;
    if (g == 3) asc = s_alpha[n] * L2E;
    #pragma unroll
    for (int rr = 0; rr < 4; ++rr) {
      int c = rt * 16 + lg * 4 + rr;
      lds_t[n][c] = f2bf(acc[cc][rr] * asc);
    }
  }
  __syncthreads();
  if (g == 0) {
    int c = tid >> 3, w0 = (tid & 7) * 16;
    int tw[8];
    #pragma unroll
    for (int i2 = 0; i2 < 8; ++i2)
      tw[i2] = (int)lds_t[w0 + 2 * i2][c] | ((int)lds_t[w0 + 2 * i2 + 1][c] << 16);
    int4* dst = reinterpret_cast<int4*>(qT + ((size_t)b * 32 + c) * 4096 + h * 128 + w0);
    dst[0] = make_int4(tw[0], tw[1], tw[2], tw[3]);
    dst[1] = make_int4(tw[4], tw[5], tw[6], tw[7]);
  } else if (tid < 128) {
    int w = tid;
    int tw[16];
    #pragma unroll
    for (int i2 = 0; i2 < 16; ++i2)
      tw[i2] = (int)lds_t[w][2 * i2] | ((int)lds_t[w][2 * i2 + 1] << 16);
    u16* base = (g == 2 || g == 4) ? Vc : KQ;
    int coff = (g >= 3) ? 32 : 0;
    int4* dst = reinterpret_cast<int4*>(base + ((size_t)b * 4096 + h * 128 + w) * 64 + coff);
    dst[0] = make_int4(tw[0],  tw[1],  tw[2],  tw[3]);
    dst[1] = make_int4(tw[4],  tw[5],  tw[6],  tw[7]);
    dst[2] = make_int4(tw[8],  tw[9],  tw[10], tw[11]);
    dst[3] = make_int4(tw[12], tw[13], tw[14], tw[15]);
  }
}

// ---------------- kernel 2: flash attention, 16-way j-split ---------------
// R12 inner loop; j-split 8 -> 16 so grid = 2048 blocks (6/CU resident by
// LDS vs 4/CU grid-capped before): +50% resident waves to overlap chains.
__global__ __launch_bounds__(256, 4) void kattn(const u16* __restrict__ qT,
    const u16* __restrict__ KQ, const u16* __restrict__ Vc,
    u16* __restrict__ pO, float* __restrict__ pl)
{
  __shared__ __align__(16) char lds_v[2][8192];
  __shared__ __align__(16) char lds_q[2][4096];
  const int b = blockIdx.y;
  const int i0 = blockIdx.x * 128;
  const int sp = blockIdx.z;
  const int jbase = sp * 256;
  const int tid = threadIdx.x, lane = tid & 63, wid = tid >> 6;
  const int l31 = lane & 31, h = lane >> 5;
  const int iw = i0 + wid * 32;

  const u16* KQb = KQ + (size_t)b * 4096 * 64;
  const u16* Vb  = Vc + (size_t)b * 4096 * 64;
  const u16* qTb = qT + (size_t)b * 32 * 4096;

  short8 bkq[4];
  #pragma unroll
  for (int c = 0; c < 4; ++c)
    bkq[c] = *reinterpret_cast<const short8*>(
        KQb + (size_t)(iw + l31) * 64 + c * 16 + h * 8);

  const int sr = tid >> 3, sx = (tid & 7) * 16;
  const int pr0 = (sr & ~12) | ((sr & 4) << 1) | ((sr & 8) >> 1);

  #pragma unroll
  for (int q = 0; q < 2; ++q) {
    int r = sr + q * 32, gr = pr0 + q * 32;
    int4 v = *reinterpret_cast<const int4*>(
        reinterpret_cast<const char*>(Vb + (size_t)(jbase + gr) * 64) + sx);
    *reinterpret_cast<int4*>(lds_v[0] + r * 128 + (sx ^ ((r & 7) << 4))) = v;
  }
  {
    int4 qv = *reinterpret_cast<const int4*>(
        qTb + (size_t)sr * 4096 + jbase + (tid & 7) * 8);
    *reinterpret_cast<int4*>(lds_q[0] + sr * 128 + (sx ^ ((sr & 7) << 4))) = qv;
  }
  __syncthreads();

  float l_run = 0.f;
  f32x16 accO = {};
  int4 stgV[2], stgQ;

  for (int t = 0; t < 4; ++t) {
    const int buf = t & 1;
    if (t < 3) {
      const u16* Vn = Vb + (size_t)(jbase + (t + 1) * 64) * 64;
      #pragma unroll
      for (int q = 0; q < 2; ++q) {
        int gr = pr0 + q * 32;
        stgV[q] = *reinterpret_cast<const int4*>(
            reinterpret_cast<const char*>(Vn + (size_t)gr * 64) + sx);
      }
      stgQ = *reinterpret_cast<const int4*>(
          qTb + (size_t)sr * 4096 + jbase + (t + 1) * 64 + (tid & 7) * 8);
    }
    f32x16 st[2];
    st[0] = f32x16{}; st[1] = f32x16{};
    __builtin_amdgcn_s_setprio(1);
    #pragma unroll
    for (int jt = 0; jt < 2; ++jt) {
      int vr = jt * 32 + l31;
      #pragma unroll
      for (int c = 0; c < 4; ++c) {
        short8 av = *reinterpret_cast<const short8*>(
            lds_v[buf] + vr * 128 + ((c * 32 + h * 16) ^ ((vr & 7) << 4)));
        st[jt] = MFMA32(av, bkq[c], st[jt]);
      }
    }
    __builtin_amdgcn_s_setprio(0);
    short8 aq[4];
    #pragma unroll
    for (int cc = 0; cc < 4; ++cc)
      aq[cc] = *reinterpret_cast<const short8*>(
          lds_q[buf] + l31 * 128 + ((cc * 32 + h * 16) ^ ((l31 & 7) << 4)));
    #pragma unroll
    for (int jt = 0; jt < 2; ++jt)
      #pragma unroll
      for (int r = 0; r < 16; ++r) {
        float p = exp2f(st[jt][r]);
        st[jt][r] = p;
        l_run += p;
      }
    __builtin_amdgcn_s_setprio(1);
    #pragma unroll
    for (int cc = 0; cc < 4; ++cc) {
      const int jt = cc >> 1, p8 = (cc & 1) * 8;
      short8 bp = mk_frag(pack_bf2(st[jt][p8 + 0], st[jt][p8 + 1]),
                          pack_bf2(st[jt][p8 + 2], st[jt][p8 + 3]),
                          pack_bf2(st[jt][p8 + 4], st[jt][p8 + 5]),
                          pack_bf2(st[jt][p8 + 6], st[jt][p8 + 7]));
      accO = MFMA32(aq[cc], bp, accO);
    }
    __builtin_amdgcn_s_setprio(0);

    if (t < 3) {
      #pragma unroll
      for (int q = 0; q < 2; ++q) {
        int r = sr + q * 32;
        *reinterpret_cast<int4*>(lds_v[buf ^ 1] + r * 128 + (sx ^ ((r & 7) << 4))) = stgV[q];
      }
      *reinterpret_cast<int4*>(lds_q[buf ^ 1] + sr * 128 + (sx ^ ((sr & 7) << 4))) = stgQ;
      __syncthreads();
    }
  }

  const int i = iw + l31;
  u16* pOb = pO + (size_t)((b * 16 + sp) * 32) * 4096;
  #pragma unroll
  for (int r = 0; r < 16; ++r) {
    int c = (r & 3) + 8 * (r >> 2) + 4 * h;
    pOb[(size_t)c * 4096 + i] = f2bf(accO[r]);
  }
  float l = half_sum(l_run);
  if (h == 0) pl[(b * 16 + sp) * 4096 + i] = l;
}

// ---------------- kernel 3: sum partials + final mix + residual -----------
__global__ __launch_bounds__(256) void kout(const u16* __restrict__ pO,
    const float* __restrict__ pl,
    const float* __restrict__ R_W, const float* __restrict__ F_W,
    const float* __restrict__ head, const float* __restrict__ tail,
    const int* __restrict__ flagp, float* __restrict__ out)
{
  __shared__ __align__(16) char btW[32768];
  __shared__ u16 ylds[16][136];
  const int flag = *flagp;
  const float* X1 = flag ? head : tail;
  const int tid = threadIdx.x;
  const int b = blockIdx.x >> 6, c = (blockIdx.x >> 1) & 31, hh = blockIdx.x & 1;
  const int rbase = b * 1024 + c * 32 + hh * 16;
  const int ioff = hh * 2048 + tid * 8;

  transpose_to_lds(flag ? R_W : F_W, btW, tid);

  #pragma unroll
  for (int iq = 0; iq < 2; ++iq) {
    float4 L4 = {0.f, 0.f, 0.f, 0.f}, y4 = {0.f, 0.f, 0.f, 0.f};
    #pragma unroll
    for (int sp = 0; sp < 16; ++sp) {
      float4 l4 = *reinterpret_cast<const float4*>(
          pl + (size_t)((b * 16 + sp) * 4096) + ioff + iq * 4);
      L4.x += l4.x; L4.y += l4.y; L4.z += l4.z; L4.w += l4.w;
      short4_t o4 = *reinterpret_cast<const short4_t*>(
          pO + (size_t)(((b * 16 + sp) * 32 + c)) * 4096 + ioff + iq * 4);
      y4.x += bf2f(o4[0]); y4.y += bf2f(o4[1]);
      y4.z += bf2f(o4[2]); y4.w += bf2f(o4[3]);
    }
    y4.x /= L4.x; y4.y /= L4.y; y4.z /= L4.z; y4.w /= L4.w;
    uint2 pk2;
    pk2.x = pack_bf2(y4.x, y4.y);
    pk2.y = pack_bf2(y4.z, y4.w);
    *reinterpret_cast<uint2*>(&ylds[tid >> 4][(tid & 15) * 8 + iq * 4]) = pk2;
  }
  __syncthreads();

  const int lane = tid & 63, wid = tid >> 6;
  const int lrow = lane & 15, lg = lane >> 4;
  const int cg = wid * 32;
  f32x4 acc[2] = {};
  #pragma unroll
  for (int k0 = 0; k0 < 128; k0 += 32) {
    short8 af = *reinterpret_cast<const short8*>(&ylds[lrow][k0 + lg * 8]);
    #pragma unroll
    for (int cc = 0; cc < 2; ++cc) {
      int n = cg + cc * 16 + lrow;
      short8 bf = *reinterpret_cast<const short8*>(
          btW + ((n * 256 + k0 * 2 + lg * 16) ^ wswz(n)));
      acc[cc] = MFMA16(af, bf, acc[cc]);
    }
  }
  #pragma unroll
  for (int cc = 0; cc < 2; ++cc)
    #pragma unroll
    for (int rr = 0; rr < 4; ++rr) {
      int row = rbase + lg * 4 + rr;
      int col = cg + cc * 16 + lrow;
      size_t idx = (size_t)row * 128 + col;
      out[idx] = acc[cc][rr] + X1[idx];
    }
}

// ---------------- launch ---------------------------------------------------
extern "C" void kernel_launch(void* const* d_in, const int* in_sizes, int n_in,
                              void* d_out, int out_size, void* d_ws, size_t ws_size,
                              hipStream_t stream)
{
  const float* head    = (const float*)d_in[0];
  const float* tail    = (const float*)d_in[1];
  const float* R_q     = (const float*)d_in[2];
  const float* R_k     = (const float*)d_in[3];
  const float* R_v     = (const float*)d_in[4];
  const float* R_W     = (const float*)d_in[5];
  const float* F_q     = (const float*)d_in[6];
  const float* F_k     = (const float*)d_in[7];
  const float* F_v     = (const float*)d_in[8];
  const float* F_W     = (const float*)d_in[9];
  const float* conv_w  = (const float*)d_in[10];
  const float* conv_b  = (const float*)d_in[11];
  const float* bn_w    = (const float*)d_in[12];
  const float* bn_b    = (const float*)d_in[13];
  const float* bn_mean = (const float*)d_in[14];
  const float* bn_var  = (const float*)d_in[15];
  const int*   flagp   = (const int*)d_in[16];
  float* out = (float*)d_out;

  char* ws = (char*)d_ws;
  u16*   qT   = (u16*)(ws + 262144);      // 1 MB   (b,32,L) bf16
  u16*   KQ   = (u16*)(ws + 1310720);     // 2 MB   (b,L,64) bf16, log2e-scaled
  u16*   Vc   = (u16*)(ws + 3407872);     // 2 MB   (b,L,64) bf16
  u16*   pO   = (u16*)(ws + 6553600);     // 16 MB  [b][16][32][L] bf16 partial sums
  float* pl   = (float*)(ws + 23330816);  // 1 MB   [b][16][L] partial denominators

  kproj <<<dim3(128, 5), 256, 0, stream>>>(head, tail, R_q, R_k, R_v,
                                           F_q, F_k, F_v, conv_w, conv_b,
                                           bn_w, bn_b, bn_mean, bn_var,
                                           qT, KQ, Vc, flagp);
  kattn <<<dim3(32, 4, 16), 256, 0, stream>>>(qT, KQ, Vc, pO, pl);
  kout  <<<256, 256, 0, stream>>>(pO, pl, R_W, F_W, head, tail, flagp, out);
}

// Round 18
// 56.770 us; speedup vs baseline: 1.2981x; 1.0076x over previous
//
#include <hip/hip_runtime.h>
#include <hip/hip_bf16.h>
#include <stdint.h>

typedef unsigned short u16;
typedef unsigned int u32;
typedef __attribute__((ext_vector_type(8))) short short8;
typedef __attribute__((ext_vector_type(4))) short short4_t;
typedef __attribute__((ext_vector_type(4))) float f32x4;
typedef __attribute__((ext_vector_type(16))) float f32x16;

#define MFMA16(A,B,C) __builtin_amdgcn_mfma_f32_16x16x32_bf16((A),(B),(C),0,0,0)
#define MFMA32(A,B,C) __builtin_amdgcn_mfma_f32_32x32x16_bf16((A),(B),(C),0,0,0)
#define L2E 1.4426950408889634f

__device__ __forceinline__ u16 f2bf(float f) {
  u32 x = __float_as_uint(f);
  u32 r = x + 0x7fffu + ((x >> 16) & 1u);
  return (u16)(r >> 16);
}
__device__ __forceinline__ float bf2f(short v) {
  return __uint_as_float((u32)(u16)v << 16);
}
__device__ __forceinline__ u32 pack_bf2(float a, float b) {
  __hip_bfloat162 h = __float22bfloat162_rn(make_float2(a, b));
  u32 u; __builtin_memcpy(&u, &h, 4); return u;
}
__device__ __forceinline__ short8 mk_frag(u32 w0, u32 w1, u32 w2, u32 w3) {
  union { u32 u[4]; short8 s; } cv;
  cv.u[0] = w0; cv.u[1] = w1; cv.u[2] = w2; cv.u[3] = w3;
  return cv.s;
}

#if __has_builtin(__builtin_amdgcn_permlane32_swap)
__device__ __forceinline__ float half_sum(float x) {
  u32 xu = __float_as_uint(x);
  auto a = __builtin_amdgcn_permlane32_swap(xu, xu, false, false);
  return __uint_as_float(a[0]) + __uint_as_float(a[1]);
}
#else
__device__ __forceinline__ float half_sum(float x) {
  return x + __shfl_xor(x, 32, 64);
}
#endif

// weight-tile swizzle: separates row stripes AND 32-col groups so transpose
// writes hit distinct bank quartets.  Bits 4..7, bijective per row.
__device__ __forceinline__ int wswz(int n) {
  return ((n & 7) ^ ((n >> 5) & 3)) << 4;
}

// In-block transpose of a 128x128 f32 matrix into a swizzled bf16 LDS tile.
__device__ __forceinline__ void transpose_to_lds(const float* __restrict__ Sg,
                                                 char* btc, int tid)
{
  const int kr = (tid >> 2) * 2;
  const int nc = (tid & 3) * 32;
  const float* r0 = Sg + kr * 128 + nc;
  const float* r1 = r0 + 128;
  #pragma unroll
  for (int j4 = 0; j4 < 8; ++j4) {
    float4 a = *reinterpret_cast<const float4*>(r0 + j4 * 4);
    float4 b = *reinterpret_cast<const float4*>(r1 + j4 * 4);
    #pragma unroll
    for (int e = 0; e < 4; ++e) {
      int n = nc + j4 * 4 + e;
      *reinterpret_cast<u32*>(btc + ((n * 256 + kr * 2) ^ wswz(n))) =
          pack_bf2((&a.x)[e], (&b.x)[e]);
    }
  }
}

// ---------------- kernel 1: 5 projections, packed layouts -----------------
__global__ __launch_bounds__(256) void kproj(const float* __restrict__ head,
    const float* __restrict__ tail,
    const float* __restrict__ R_q, const float* __restrict__ R_k,
    const float* __restrict__ R_v, const float* __restrict__ F_q,
    const float* __restrict__ F_k, const float* __restrict__ F_v,
    const float* __restrict__ conv_w, const float* __restrict__ conv_b,
    const float* __restrict__ bn_w, const float* __restrict__ bn_b,
    const float* __restrict__ bn_mean, const float* __restrict__ bn_var,
    u16* __restrict__ qT, u16* __restrict__ KQ,
    u16* __restrict__ Vc, const int* __restrict__ flagp)
{
  __shared__ __align__(16) char bt[32768];
  __shared__ u16 lds_t[128][34];
  __shared__ float s_alpha[128];
  const int flag = *flagp;
  const float* X1 = flag ? head : tail;
  const float* X2 = flag ? tail : head;
  const int bh = blockIdx.x, g = blockIdx.y;
  const int b = bh >> 5, h = bh & 31;
  const float* src = (g < 3) ? X1 : X2;
  const int tid = threadIdx.x, lane = tid & 63, wid = tid >> 6;
  const int lrow = lane & 15, lg = lane >> 4;
  const int rt = wid & 1, cbase = (wid >> 1) * 64;

  {
    const float* s1[5] = {R_q, R_k, R_v, F_k, F_v};
    const float* s0[5] = {F_q, F_k, F_v, R_k, R_v};
    transpose_to_lds(flag ? s1[g] : s0[g], bt, tid);
  }

  if (g == 3) {
    if (tid < 128) {
      int w = tid;
      const float* hp = head + ((size_t)b * 1024 + h) * 128 + w;
      const float* tp = tail + ((size_t)b * 1024 + h) * 128 + w;
      float a0 = 0.f, a1 = 0.f;
      for (int c = 0; c < 32; ++c) {
        float xh = hp[c * 4096];
        float xt = tp[c * 4096];
        a0 += xh * conv_w[c]      + xt * conv_w[32 + c];
        a1 += xh * conv_w[64 + c] + xt * conv_w[96 + c];
      }
      const float eps = 1e-5f;
      a0 += conv_b[0]; a1 += conv_b[1];
      a0 = (a0 - bn_mean[0]) * (bn_w[0] * rsqrtf(bn_var[0] + eps)) + bn_b[0];
      a1 = (a1 - bn_mean[1]) * (bn_w[1] * rsqrtf(bn_var[1] + eps)) + bn_b[1];
      a0 = fmaxf(a0, 0.f); a1 = fmaxf(a1, 0.f);
      float asel = flag ? a0 : a1, aoth = flag ? a1 : a0;
      s_alpha[w] = 1.f / (1.f + __expf(aoth - asel));
    }
  }
  __syncthreads();

  f32x4 acc[4] = {};
  const float* Arow = src + (((size_t)b * 32 + rt * 16 + lrow) * 32 + h) * 128;
  #pragma unroll
  for (int k0 = 0; k0 < 128; k0 += 32) {
    const float* ap = Arow + k0 + lg * 8;
    float4 f0 = *reinterpret_cast<const float4*>(ap);
    float4 f1 = *reinterpret_cast<const float4*>(ap + 4);
    short8 af = mk_frag(pack_bf2(f0.x, f0.y), pack_bf2(f0.z, f0.w),
                        pack_bf2(f1.x, f1.y), pack_bf2(f1.z, f1.w));
    #pragma unroll
    for (int cc = 0; cc < 4; ++cc) {
      int n = cbase + cc * 16 + lrow;
      short8 bf = *reinterpret_cast<const short8*>(
          bt + ((n * 256 + k0 * 2 + lg * 16) ^ wswz(n)));
      acc[cc] = MFMA16(af, bf, acc[cc]);
    }
  }
  #pragma unroll
  for (int cc = 0; cc < 4; ++cc) {
    int n = cbase + cc * 16 + lrow;
    float asc = (g == 1) ? L2E : 1.f;
    if (g == 3) asc = s_alpha[n] * L2E;
    #pragma unroll
    for (int rr = 0; rr < 4; ++rr) {
      int c = rt * 16 + lg * 4 + rr;
      lds_t[n][c] = f2bf(acc[cc][rr] * asc);
    }
  }
  __syncthreads();
  if (g == 0) {
    int c = tid >> 3, w0 = (tid & 7) * 16;
    int tw[8];
    #pragma unroll
    for (int i2 = 0; i2 < 8; ++i2)
      tw[i2] = (int)lds_t[w0 + 2 * i2][c] | ((int)lds_t[w0 + 2 * i2 + 1][c] << 16);
    int4* dst = reinterpret_cast<int4*>(qT + ((size_t)b * 32 + c) * 4096 + h * 128 + w0);
    dst[0] = make_int4(tw[0], tw[1], tw[2], tw[3]);
    dst[1] = make_int4(tw[4], tw[5], tw[6], tw[7]);
  } else if (tid < 128) {
    int w = tid;
    int tw[16];
    #pragma unroll
    for (int i2 = 0; i2 < 16; ++i2)
      tw[i2] = (int)lds_t[w][2 * i2] | ((int)lds_t[w][2 * i2 + 1] << 16);
    u16* base = (g == 2 || g == 4) ? Vc : KQ;
    int coff = (g >= 3) ? 32 : 0;
    int4* dst = reinterpret_cast<int4*>(base + ((size_t)b * 4096 + h * 128 + w) * 64 + coff);
    dst[0] = make_int4(tw[0],  tw[1],  tw[2],  tw[3]);
    dst[1] = make_int4(tw[4],  tw[5],  tw[6],  tw[7]);
    dst[2] = make_int4(tw[8],  tw[9],  tw[10], tw[11]);
    dst[3] = make_int4(tw[12], tw[13], tw[14], tw[15]);
  }
}

// ---------------- kernel 2: flash attention, 2-deep prefetch --------------
// R15 inner loop; staging pipeline deepened to TWO tiles in flight
// (triple-buffered LDS): iter t computes lds[t%3], writes tile t+1 (loads
// issued 2 iters earlier -> ~1400cy latency budget vs ~600 before, covering
// cross-XCD L3 latency), then issues tile t+3 into the freed register set.
// Register sets alternate A (even t) / B (odd t) -- fully static indices.
__global__ __launch_bounds__(256, 4) void kattn(const u16* __restrict__ qT,
    const u16* __restrict__ KQ, const u16* __restrict__ Vc,
    u16* __restrict__ pO, float* __restrict__ pl)
{
  __shared__ __align__(16) char lds_v[3][8192];
  __shared__ __align__(16) char lds_q[3][4096];
  const int b = blockIdx.y;
  const int i0 = blockIdx.x * 128;
  const int sp = blockIdx.z;
  const int jbase = sp * 512;
  const int tid = threadIdx.x, lane = tid & 63, wid = tid >> 6;
  const int l31 = lane & 31, h = lane >> 5;
  const int iw = i0 + wid * 32;

  const u16* KQb = KQ + (size_t)b * 4096 * 64;
  const u16* Vb  = Vc + (size_t)b * 4096 * 64;
  const u16* qTb = qT + (size_t)b * 32 * 4096;

  short8 bkq[4];
  #pragma unroll
  for (int c = 0; c < 4; ++c)
    bkq[c] = *reinterpret_cast<const short8*>(
        KQb + (size_t)(iw + l31) * 64 + c * 16 + h * 8);

  const int sr = tid >> 3, sx = (tid & 7) * 16;
  const int pr0 = (sr & ~12) | ((sr & 4) << 1) | ((sr & 8) >> 1);

  // stage tile 0 direct
  #pragma unroll
  for (int q = 0; q < 2; ++q) {
    int r = sr + q * 32, gr = pr0 + q * 32;
    int4 v = *reinterpret_cast<const int4*>(
        reinterpret_cast<const char*>(Vb + (size_t)(jbase + gr) * 64) + sx);
    *reinterpret_cast<int4*>(lds_v[0] + r * 128 + (sx ^ ((r & 7) << 4))) = v;
  }
  {
    int4 qv = *reinterpret_cast<const int4*>(
        qTb + (size_t)sr * 4096 + jbase + (tid & 7) * 8);
    *reinterpret_cast<int4*>(lds_q[0] + sr * 128 + (sx ^ ((sr & 7) << 4))) = qv;
  }
  // issue tile 1 -> set A, tile 2 -> set B
  int4 stgVA[2], stgVB[2], stgQA, stgQB;
  #pragma unroll
  for (int q = 0; q < 2; ++q) {
    int gr = pr0 + q * 32;
    stgVA[q] = *reinterpret_cast<const int4*>(
        reinterpret_cast<const char*>(Vb + (size_t)(jbase + 64 + gr) * 64) + sx);
  }
  stgQA = *reinterpret_cast<const int4*>(
      qTb + (size_t)sr * 4096 + jbase + 64 + (tid & 7) * 8);
  #pragma unroll
  for (int q = 0; q < 2; ++q) {
    int gr = pr0 + q * 32;
    stgVB[q] = *reinterpret_cast<const int4*>(
        reinterpret_cast<const char*>(Vb + (size_t)(jbase + 128 + gr) * 64) + sx);
  }
  stgQB = *reinterpret_cast<const int4*>(
      qTb + (size_t)sr * 4096 + jbase + 128 + (tid & 7) * 8);
  __syncthreads();

  float l_run = 0.f;
  f32x16 accO = {};

  #pragma unroll
  for (int t = 0; t < 8; ++t) {
    const int cur = t % 3;
    f32x16 st[2];
    st[0] = f32x16{}; st[1] = f32x16{};
    __builtin_amdgcn_s_setprio(1);
    #pragma unroll
    for (int jt = 0; jt < 2; ++jt) {
      int vr = jt * 32 + l31;
      #pragma unroll
      for (int c = 0; c < 4; ++c) {
        short8 av = *reinterpret_cast<const short8*>(
            lds_v[cur] + vr * 128 + ((c * 32 + h * 16) ^ ((vr & 7) << 4)));
        st[jt] = MFMA32(av, bkq[c], st[jt]);
      }
    }
    __builtin_amdgcn_s_setprio(0);
    short8 aq[4];
    #pragma unroll
    for (int cc = 0; cc < 4; ++cc)
      aq[cc] = *reinterpret_cast<const short8*>(
          lds_q[cur] + l31 * 128 + ((cc * 32 + h * 16) ^ ((l31 & 7) << 4)));
    #pragma unroll
    for (int jt = 0; jt < 2; ++jt)
      #pragma unroll
      for (int r = 0; r < 16; ++r) {
        float p = exp2f(st[jt][r]);
        st[jt][r] = p;
        l_run += p;
      }
    __builtin_amdgcn_s_setprio(1);
    #pragma unroll
    for (int cc = 0; cc < 4; ++cc) {
      const int jt = cc >> 1, p8 = (cc & 1) * 8;
      short8 bp = mk_frag(pack_bf2(st[jt][p8 + 0], st[jt][p8 + 1]),
                          pack_bf2(st[jt][p8 + 2], st[jt][p8 + 3]),
                          pack_bf2(st[jt][p8 + 4], st[jt][p8 + 5]),
                          pack_bf2(st[jt][p8 + 6], st[jt][p8 + 7]));
      accO = MFMA32(aq[cc], bp, accO);
    }
    __builtin_amdgcn_s_setprio(0);

    if (t < 7) {
      const int nxt = (t + 1) % 3;
      if ((t & 1) == 0) {
        // write tile t+1 from set A (loads 2 iters old)
        #pragma unroll
        for (int q = 0; q < 2; ++q) {
          int r = sr + q * 32;
          *reinterpret_cast<int4*>(lds_v[nxt] + r * 128 + (sx ^ ((r & 7) << 4))) = stgVA[q];
        }
        *reinterpret_cast<int4*>(lds_q[nxt] + sr * 128 + (sx ^ ((sr & 7) << 4))) = stgQA;
        if (t <= 4) {                   // issue tile t+3 into freed set A
          const u16* Vn = Vb + (size_t)(jbase + (t + 3) * 64) * 64;
          #pragma unroll
          for (int q = 0; q < 2; ++q) {
            int gr = pr0 + q * 32;
            stgVA[q] = *reinterpret_cast<const int4*>(
                reinterpret_cast<const char*>(Vn + (size_t)gr * 64) + sx);
          }
          stgQA = *reinterpret_cast<const int4*>(
              qTb + (size_t)sr * 4096 + jbase + (t + 3) * 64 + (tid & 7) * 8);
        }
      } else {
        #pragma unroll
        for (int q = 0; q < 2; ++q) {
          int r = sr + q * 32;
          *reinterpret_cast<int4*>(lds_v[nxt] + r * 128 + (sx ^ ((r & 7) << 4))) = stgVB[q];
        }
        *reinterpret_cast<int4*>(lds_q[nxt] + sr * 128 + (sx ^ ((sr & 7) << 4))) = stgQB;
        if (t <= 4) {
          const u16* Vn = Vb + (size_t)(jbase + (t + 3) * 64) * 64;
          #pragma unroll
          for (int q = 0; q < 2; ++q) {
            int gr = pr0 + q * 32;
            stgVB[q] = *reinterpret_cast<const int4*>(
                reinterpret_cast<const char*>(Vn + (size_t)gr * 64) + sx);
          }
          stgQB = *reinterpret_cast<const int4*>(
              qTb + (size_t)sr * 4096 + jbase + (t + 3) * 64 + (tid & 7) * 8);
        }
      }
      __syncthreads();
    }
  }

  const int i = iw + l31;
  u16* pOb = pO + (size_t)((b * 8 + sp) * 32) * 4096;
  #pragma unroll
  for (int r = 0; r < 16; ++r) {
    int c = (r & 3) + 8 * (r >> 2) + 4 * h;
    pOb[(size_t)c * 4096 + i] = f2bf(accO[r]);
  }
  float l = half_sum(l_run);
  if (h == 0) pl[(b * 8 + sp) * 4096 + i] = l;
}

// ---------------- kernel 3: sum partials + final mix + residual -----------
__global__ __launch_bounds__(256) void kout(const u16* __restrict__ pO,
    const float* __restrict__ pl,
    const float* __restrict__ R_W, const float* __restrict__ F_W,
    const float* __restrict__ head, const float* __restrict__ tail,
    const int* __restrict__ flagp, float* __restrict__ out)
{
  __shared__ __align__(16) char btW[32768];
  __shared__ u16 ylds[16][136];
  const int flag = *flagp;
  const float* X1 = flag ? head : tail;
  const int tid = threadIdx.x;
  const int b = blockIdx.x >> 6, c = (blockIdx.x >> 1) & 31, hh = blockIdx.x & 1;
  const int rbase = b * 1024 + c * 32 + hh * 16;
  const int ioff = hh * 2048 + tid * 8;

  transpose_to_lds(flag ? R_W : F_W, btW, tid);

  #pragma unroll
  for (int iq = 0; iq < 2; ++iq) {
    float4 L4 = {0.f, 0.f, 0.f, 0.f}, y4 = {0.f, 0.f, 0.f, 0.f};
    #pragma unroll
    for (int sp = 0; sp < 8; ++sp) {
      float4 l4 = *reinterpret_cast<const float4*>(
          pl + (size_t)((b * 8 + sp) * 4096) + ioff + iq * 4);
      L4.x += l4.x; L4.y += l4.y; L4.z += l4.z; L4.w += l4.w;
      short4_t o4 = *reinterpret_cast<const short4_t*>(
          pO + (size_t)(((b * 8 + sp) * 32 + c)) * 4096 + ioff + iq * 4);
      y4.x += bf2f(o4[0]); y4.y += bf2f(o4[1]);
      y4.z += bf2f(o4[2]); y4.w += bf2f(o4[3]);
    }
    y4.x /= L4.x; y4.y /= L4.y; y4.z /= L4.z; y4.w /= L4.w;
    uint2 pk2;
    pk2.x = pack_bf2(y4.x, y4.y);
    pk2.y = pack_bf2(y4.z, y4.w);
    *reinterpret_cast<uint2*>(&ylds[tid >> 4][(tid & 15) * 8 + iq * 4]) = pk2;
  }
  __syncthreads();

  const int lane = tid & 63, wid = tid >> 6;
  const int lrow = lane & 15, lg = lane >> 4;
  const int cg = wid * 32;
  f32x4 acc[2] = {};
  #pragma unroll
  for (int k0 = 0; k0 < 128; k0 += 32) {
    short8 af = *reinterpret_cast<const short8*>(&ylds[lrow][k0 + lg * 8]);
    #pragma unroll
    for (int cc = 0; cc < 2; ++cc) {
      int n = cg + cc * 16 + lrow;
      short8 bf = *reinterpret_cast<const short8*>(
          btW + ((n * 256 + k0 * 2 + lg * 16) ^ wswz(n)));
      acc[cc] = MFMA16(af, bf, acc[cc]);
    }
  }
  #pragma unroll
  for (int cc = 0; cc < 2; ++cc)
    #pragma unroll
    for (int rr = 0; rr < 4; ++rr) {
      int row = rbase + lg * 4 + rr;
      int col = cg + cc * 16 + lrow;
      size_t idx = (size_t)row * 128 + col;
      out[idx] = acc[cc][rr] + X1[idx];
    }
}

// ---------------- launch ---------------------------------------------------
extern "C" void kernel_launch(void* const* d_in, const int* in_sizes, int n_in,
                              void* d_out, int out_size, void* d_ws, size_t ws_size,
                              hipStream_t stream)
{
  const float* head    = (const float*)d_in[0];
  const float* tail    = (const float*)d_in[1];
  const float* R_q     = (const float*)d_in[2];
  const float* R_k     = (const float*)d_in[3];
  const float* R_v     = (const float*)d_in[4];
  const float* R_W     = (const float*)d_in[5];
  const float* F_q     = (const float*)d_in[6];
  const float* F_k     = (const float*)d_in[7];
  const float* F_v     = (const float*)d_in[8];
  const float* F_W     = (const float*)d_in[9];
  const float* conv_w  = (const float*)d_in[10];
  const float* conv_b  = (const float*)d_in[11];
  const float* bn_w    = (const float*)d_in[12];
  const float* bn_b    = (const float*)d_in[13];
  const float* bn_mean = (const float*)d_in[14];
  const float* bn_var  = (const float*)d_in[15];
  const int*   flagp   = (const int*)d_in[16];
  float* out = (float*)d_out;

  char* ws = (char*)d_ws;
  u16*   qT   = (u16*)(ws + 262144);      // 1 MB   (b,32,L) bf16
  u16*   KQ   = (u16*)(ws + 1310720);     // 2 MB   (b,L,64) bf16, log2e-scaled
  u16*   Vc   = (u16*)(ws + 3407872);     // 2 MB   (b,L,64) bf16
  u16*   pO   = (u16*)(ws + 6553600);     // 8 MB   [b][8][32][L] bf16 partial sums
  float* pl   = (float*)(ws + 14942208);  // 512 KB [b][8][L] partial denominators

  kproj <<<dim3(128, 5), 256, 0, stream>>>(head, tail, R_q, R_k, R_v,
                                           F_q, F_k, F_v, conv_w, conv_b,
                                           bn_w, bn_b, bn_mean, bn_var,
                                           qT, KQ, Vc, flagp);
  kattn <<<dim3(32, 4, 8), 256, 0, stream>>>(qT, KQ, Vc, pO, pl);
  kout  <<<256, 256, 0, stream>>>(pO, pl, R_W, F_W, head, tail, flagp, out);
}

// Round 19
// 55.766 us; speedup vs baseline: 1.3215x; 1.0180x over previous
//
#include <hip/hip_runtime.h>
#include <hip/hip_bf16.h>
#include <stdint.h>

typedef unsigned short u16;
typedef unsigned int u32;
typedef __attribute__((ext_vector_type(8))) short short8;
typedef __attribute__((ext_vector_type(4))) short short4_t;
typedef __attribute__((ext_vector_type(4))) float f32x4;
typedef __attribute__((ext_vector_type(16))) float f32x16;

#define MFMA16(A,B,C) __builtin_amdgcn_mfma_f32_16x16x32_bf16((A),(B),(C),0,0,0)
#define MFMA32(A,B,C) __builtin_amdgcn_mfma_f32_32x32x16_bf16((A),(B),(C),0,0,0)
#define L2E 1.4426950408889634f

__device__ __forceinline__ u16 f2bf(float f) {
  u32 x = __float_as_uint(f);
  u32 r = x + 0x7fffu + ((x >> 16) & 1u);
  return (u16)(r >> 16);
}
__device__ __forceinline__ float bf2f(short v) {
  return __uint_as_float((u32)(u16)v << 16);
}
__device__ __forceinline__ u32 pack_bf2(float a, float b) {
  __hip_bfloat162 h = __float22bfloat162_rn(make_float2(a, b));
  u32 u; __builtin_memcpy(&u, &h, 4); return u;
}
__device__ __forceinline__ short8 mk_frag(u32 w0, u32 w1, u32 w2, u32 w3) {
  union { u32 u[4]; short8 s; } cv;
  cv.u[0] = w0; cv.u[1] = w1; cv.u[2] = w2; cv.u[3] = w3;
  return cv.s;
}

#if __has_builtin(__builtin_amdgcn_permlane32_swap)
__device__ __forceinline__ float half_sum(float x) {
  u32 xu = __float_as_uint(x);
  auto a = __builtin_amdgcn_permlane32_swap(xu, xu, false, false);
  return __uint_as_float(a[0]) + __uint_as_float(a[1]);
}
#else
__device__ __forceinline__ float half_sum(float x) {
  return x + __shfl_xor(x, 32, 64);
}
#endif

// weight-tile swizzle: separates row stripes AND 32-col groups so transpose
// writes hit distinct bank quartets.  Bits 4..7, bijective per row.
__device__ __forceinline__ int wswz(int n) {
  return ((n & 7) ^ ((n >> 5) & 3)) << 4;
}

// In-block transpose of a 128x128 f32 matrix into a swizzled bf16 LDS tile.
__device__ __forceinline__ void transpose_to_lds(const float* __restrict__ Sg,
                                                 char* btc, int tid)
{
  const int kr = (tid >> 2) * 2;
  const int nc = (tid & 3) * 32;
  const float* r0 = Sg + kr * 128 + nc;
  const float* r1 = r0 + 128;
  #pragma unroll
  for (int j4 = 0; j4 < 8; ++j4) {
    float4 a = *reinterpret_cast<const float4*>(r0 + j4 * 4);
    float4 b = *reinterpret_cast<const float4*>(r1 + j4 * 4);
    #pragma unroll
    for (int e = 0; e < 4; ++e) {
      int n = nc + j4 * 4 + e;
      *reinterpret_cast<u32*>(btc + ((n * 256 + kr * 2) ^ wswz(n))) =
          pack_bf2((&a.x)[e], (&b.x)[e]);
    }
  }
}

// ---------------- kernel 1: 5 projections, packed layouts -----------------
__global__ __launch_bounds__(256) void kproj(const float* __restrict__ head,
    const float* __restrict__ tail,
    const float* __restrict__ R_q, const float* __restrict__ R_k,
    const float* __restrict__ R_v, const float* __restrict__ F_q,
    const float* __restrict__ F_k, const float* __restrict__ F_v,
    const float* __restrict__ conv_w, const float* __restrict__ conv_b,
    const float* __restrict__ bn_w, const float* __restrict__ bn_b,
    const float* __restrict__ bn_mean, const float* __restrict__ bn_var,
    u16* __restrict__ qT, u16* __restrict__ KQ,
    u16* __restrict__ Vc, const int* __restrict__ flagp)
{
  __shared__ __align__(16) char bt[32768];
  __shared__ u16 lds_t[128][34];
  __shared__ float s_alpha[128];
  const int flag = *flagp;
  const float* X1 = flag ? head : tail;
  const float* X2 = flag ? tail : head;
  const int bh = blockIdx.x, g = blockIdx.y;
  const int b = bh >> 5, h = bh & 31;
  const float* src = (g < 3) ? X1 : X2;
  const int tid = threadIdx.x, lane = tid & 63, wid = tid >> 6;
  const int lrow = lane & 15, lg = lane >> 4;
  const int rt = wid & 1, cbase = (wid >> 1) * 64;

  {
    const float* s1[5] = {R_q, R_k, R_v, F_k, F_v};
    const float* s0[5] = {F_q, F_k, F_v, R_k, R_v};
    transpose_to_lds(flag ? s1[g] : s0[g], bt, tid);
  }

  if (g == 3) {
    if (tid < 128) {
      int w = tid;
      const float* hp = head + ((size_t)b * 1024 + h) * 128 + w;
      const float* tp = tail + ((size_t)b * 1024 + h) * 128 + w;
      float a0 = 0.f, a1 = 0.f;
      for (int c = 0; c < 32; ++c) {
        float xh = hp[c * 4096];
        float xt = tp[c * 4096];
        a0 += xh * conv_w[c]      + xt * conv_w[32 + c];
        a1 += xh * conv_w[64 + c] + xt * conv_w[96 + c];
      }
      const float eps = 1e-5f;
      a0 += conv_b[0]; a1 += conv_b[1];
      a0 = (a0 - bn_mean[0]) * (bn_w[0] * rsqrtf(bn_var[0] + eps)) + bn_b[0];
      a1 = (a1 - bn_mean[1]) * (bn_w[1] * rsqrtf(bn_var[1] + eps)) + bn_b[1];
      a0 = fmaxf(a0, 0.f); a1 = fmaxf(a1, 0.f);
      float asel = flag ? a0 : a1, aoth = flag ? a1 : a0;
      s_alpha[w] = 1.f / (1.f + __expf(aoth - asel));
    }
  }
  __syncthreads();

  f32x4 acc[4] = {};
  const float* Arow = src + (((size_t)b * 32 + rt * 16 + lrow) * 32 + h) * 128;
  #pragma unroll
  for (int k0 = 0; k0 < 128; k0 += 32) {
    const float* ap = Arow + k0 + lg * 8;
    float4 f0 = *reinterpret_cast<const float4*>(ap);
    float4 f1 = *reinterpret_cast<const float4*>(ap + 4);
    short8 af = mk_frag(pack_bf2(f0.x, f0.y), pack_bf2(f0.z, f0.w),
                        pack_bf2(f1.x, f1.y), pack_bf2(f1.z, f1.w));
    #pragma unroll
    for (int cc = 0; cc < 4; ++cc) {
      int n = cbase + cc * 16 + lrow;
      short8 bf = *reinterpret_cast<const short8*>(
          bt + ((n * 256 + k0 * 2 + lg * 16) ^ wswz(n)));
      acc[cc] = MFMA16(af, bf, acc[cc]);
    }
  }
  #pragma unroll
  for (int cc = 0; cc < 4; ++cc) {
    int n = cbase + cc * 16 + lrow;
    float asc = (g == 1) ? L2E : 1.f;
    if (g == 3) asc = s_alpha[n] * L2E;
    #pragma unroll
    for (int rr = 0; rr < 4; ++rr) {
      int c = rt * 16 + lg * 4 + rr;
      lds_t[n][c] = f2bf(acc[cc][rr] * asc);
    }
  }
  __syncthreads();
  if (g == 0) {
    int c = tid >> 3, w0 = (tid & 7) * 16;
    int tw[8];
    #pragma unroll
    for (int i2 = 0; i2 < 8; ++i2)
      tw[i2] = (int)lds_t[w0 + 2 * i2][c] | ((int)lds_t[w0 + 2 * i2 + 1][c] << 16);
    int4* dst = reinterpret_cast<int4*>(qT + ((size_t)b * 32 + c) * 4096 + h * 128 + w0);
    dst[0] = make_int4(tw[0], tw[1], tw[2], tw[3]);
    dst[1] = make_int4(tw[4], tw[5], tw[6], tw[7]);
  } else if (tid < 128) {
    int w = tid;
    int tw[16];
    #pragma unroll
    for (int i2 = 0; i2 < 16; ++i2)
      tw[i2] = (int)lds_t[w][2 * i2] | ((int)lds_t[w][2 * i2 + 1] << 16);
    u16* base = (g == 2 || g == 4) ? Vc : KQ;
    int coff = (g >= 3) ? 32 : 0;
    int4* dst = reinterpret_cast<int4*>(base + ((size_t)b * 4096 + h * 128 + w) * 64 + coff);
    dst[0] = make_int4(tw[0],  tw[1],  tw[2],  tw[3]);
    dst[1] = make_int4(tw[4],  tw[5],  tw[6],  tw[7]);
    dst[2] = make_int4(tw[8],  tw[9],  tw[10], tw[11]);
    dst[3] = make_int4(tw[12], tw[13], tw[14], tw[15]);
  }
}

// ---------------- kernel 2: flash attention, XCD-group swizzle ------------
// R15 inner loop.  Grid flattened to 1D (1024) and remapped so the 32
// blocks sharing one (b,sp) V/Q slice (~100 KB) get wgids with the same
// residue mod 8 -> under round-robin wgid->XCD dispatch they land on ONE
// XCD's 32 CUs, so the slice is pulled into that XCD's private L2 once and
// the other 31 blocks hit local L2 instead of far L3 (T1; correctness is
// mapping-independent per G16).
//   wgid = member*8 + (group&7) + (group>>3)*256,  group = b*8+sp.
__global__ __launch_bounds__(256, 4) void kattn(const u16* __restrict__ qT,
    const u16* __restrict__ KQ, const u16* __restrict__ Vc,
    u16* __restrict__ pO, float* __restrict__ pl)
{
  __shared__ __align__(16) char lds_v[2][8192];
  __shared__ __align__(16) char lds_q[2][4096];
  const int wg = blockIdx.x;
  const int grp = (wg >> 8) * 8 + (wg & 7);   // (b,sp) group, co-XCD
  const int b = grp >> 3, sp = grp & 7;
  const int i0 = ((wg >> 3) & 31) * 128;
  const int jbase = sp * 512;
  const int tid = threadIdx.x, lane = tid & 63, wid = tid >> 6;
  const int l31 = lane & 31, h = lane >> 5;
  const int iw = i0 + wid * 32;

  const u16* KQb = KQ + (size_t)b * 4096 * 64;
  const u16* Vb  = Vc + (size_t)b * 4096 * 64;
  const u16* qTb = qT + (size_t)b * 32 * 4096;

  short8 bkq[4];
  #pragma unroll
  for (int c = 0; c < 4; ++c)
    bkq[c] = *reinterpret_cast<const short8*>(
        KQb + (size_t)(iw + l31) * 64 + c * 16 + h * 8);

  const int sr = tid >> 3, sx = (tid & 7) * 16;
  const int pr0 = (sr & ~12) | ((sr & 4) << 1) | ((sr & 8) >> 1);

  #pragma unroll
  for (int q = 0; q < 2; ++q) {
    int r = sr + q * 32, gr = pr0 + q * 32;
    int4 v = *reinterpret_cast<const int4*>(
        reinterpret_cast<const char*>(Vb + (size_t)(jbase + gr) * 64) + sx);
    *reinterpret_cast<int4*>(lds_v[0] + r * 128 + (sx ^ ((r & 7) << 4))) = v;
  }
  {
    int4 qv = *reinterpret_cast<const int4*>(
        qTb + (size_t)sr * 4096 + jbase + (tid & 7) * 8);
    *reinterpret_cast<int4*>(lds_q[0] + sr * 128 + (sx ^ ((sr & 7) << 4))) = qv;
  }
  __syncthreads();

  float l_run = 0.f;
  f32x16 accO = {};
  int4 stgV[2], stgQ;

  for (int t = 0; t < 8; ++t) {
    const int buf = t & 1;
    if (t < 7) {
      const u16* Vn = Vb + (size_t)(jbase + (t + 1) * 64) * 64;
      #pragma unroll
      for (int q = 0; q < 2; ++q) {
        int gr = pr0 + q * 32;
        stgV[q] = *reinterpret_cast<const int4*>(
            reinterpret_cast<const char*>(Vn + (size_t)gr * 64) + sx);
      }
      stgQ = *reinterpret_cast<const int4*>(
          qTb + (size_t)sr * 4096 + jbase + (t + 1) * 64 + (tid & 7) * 8);
    }
    f32x16 st[2];
    st[0] = f32x16{}; st[1] = f32x16{};
    __builtin_amdgcn_s_setprio(1);
    #pragma unroll
    for (int jt = 0; jt < 2; ++jt) {
      int vr = jt * 32 + l31;
      #pragma unroll
      for (int c = 0; c < 4; ++c) {
        short8 av = *reinterpret_cast<const short8*>(
            lds_v[buf] + vr * 128 + ((c * 32 + h * 16) ^ ((vr & 7) << 4)));
        st[jt] = MFMA32(av, bkq[c], st[jt]);
      }
    }
    __builtin_amdgcn_s_setprio(0);
    short8 aq[4];
    #pragma unroll
    for (int cc = 0; cc < 4; ++cc)
      aq[cc] = *reinterpret_cast<const short8*>(
          lds_q[buf] + l31 * 128 + ((cc * 32 + h * 16) ^ ((l31 & 7) << 4)));
    #pragma unroll
    for (int jt = 0; jt < 2; ++jt)
      #pragma unroll
      for (int r = 0; r < 16; ++r) {
        float p = exp2f(st[jt][r]);
        st[jt][r] = p;
        l_run += p;
      }
    __builtin_amdgcn_s_setprio(1);
    #pragma unroll
    for (int cc = 0; cc < 4; ++cc) {
      const int jt = cc >> 1, p8 = (cc & 1) * 8;
      short8 bp = mk_frag(pack_bf2(st[jt][p8 + 0], st[jt][p8 + 1]),
                          pack_bf2(st[jt][p8 + 2], st[jt][p8 + 3]),
                          pack_bf2(st[jt][p8 + 4], st[jt][p8 + 5]),
                          pack_bf2(st[jt][p8 + 6], st[jt][p8 + 7]));
      accO = MFMA32(aq[cc], bp, accO);
    }
    __builtin_amdgcn_s_setprio(0);

    if (t < 7) {
      #pragma unroll
      for (int q = 0; q < 2; ++q) {
        int r = sr + q * 32;
        *reinterpret_cast<int4*>(lds_v[buf ^ 1] + r * 128 + (sx ^ ((r & 7) << 4))) = stgV[q];
      }
      *reinterpret_cast<int4*>(lds_q[buf ^ 1] + sr * 128 + (sx ^ ((sr & 7) << 4))) = stgQ;
      __syncthreads();
    }
  }

  const int i = iw + l31;
  u16* pOb = pO + (size_t)((b * 8 + sp) * 32) * 4096;
  #pragma unroll
  for (int r = 0; r < 16; ++r) {
    int c = (r & 3) + 8 * (r >> 2) + 4 * h;
    pOb[(size_t)c * 4096 + i] = f2bf(accO[r]);
  }
  float l = half_sum(l_run);
  if (h == 0) pl[(b * 8 + sp) * 4096 + i] = l;
}

// ---------------- kernel 3: sum partials + final mix + residual -----------
__global__ __launch_bounds__(256) void kout(const u16* __restrict__ pO,
    const float* __restrict__ pl,
    const float* __restrict__ R_W, const float* __restrict__ F_W,
    const float* __restrict__ head, const float* __restrict__ tail,
    const int* __restrict__ flagp, float* __restrict__ out)
{
  __shared__ __align__(16) char btW[32768];
  __shared__ u16 ylds[16][136];
  const int flag = *flagp;
  const float* X1 = flag ? head : tail;
  const int tid = threadIdx.x;
  const int b = blockIdx.x >> 6, c = (blockIdx.x >> 1) & 31, hh = blockIdx.x & 1;
  const int rbase = b * 1024 + c * 32 + hh * 16;
  const int ioff = hh * 2048 + tid * 8;

  transpose_to_lds(flag ? R_W : F_W, btW, tid);

  #pragma unroll
  for (int iq = 0; iq < 2; ++iq) {
    float4 L4 = {0.f, 0.f, 0.f, 0.f}, y4 = {0.f, 0.f, 0.f, 0.f};
    #pragma unroll
    for (int sp = 0; sp < 8; ++sp) {
      float4 l4 = *reinterpret_cast<const float4*>(
          pl + (size_t)((b * 8 + sp) * 4096) + ioff + iq * 4);
      L4.x += l4.x; L4.y += l4.y; L4.z += l4.z; L4.w += l4.w;
      short4_t o4 = *reinterpret_cast<const short4_t*>(
          pO + (size_t)(((b * 8 + sp) * 32 + c)) * 4096 + ioff + iq * 4);
      y4.x += bf2f(o4[0]); y4.y += bf2f(o4[1]);
      y4.z += bf2f(o4[2]); y4.w += bf2f(o4[3]);
    }
    y4.x /= L4.x; y4.y /= L4.y; y4.z /= L4.z; y4.w /= L4.w;
    uint2 pk2;
    pk2.x = pack_bf2(y4.x, y4.y);
    pk2.y = pack_bf2(y4.z, y4.w);
    *reinterpret_cast<uint2*>(&ylds[tid >> 4][(tid & 15) * 8 + iq * 4]) = pk2;
  }
  __syncthreads();

  const int lane = tid & 63, wid = tid >> 6;
  const int lrow = lane & 15, lg = lane >> 4;
  const int cg = wid * 32;
  f32x4 acc[2] = {};
  #pragma unroll
  for (int k0 = 0; k0 < 128; k0 += 32) {
    short8 af = *reinterpret_cast<const short8*>(&ylds[lrow][k0 + lg * 8]);
    #pragma unroll
    for (int cc = 0; cc < 2; ++cc) {
      int n = cg + cc * 16 + lrow;
      short8 bf = *reinterpret_cast<const short8*>(
          btW + ((n * 256 + k0 * 2 + lg * 16) ^ wswz(n)));
      acc[cc] = MFMA16(af, bf, acc[cc]);
    }
  }
  #pragma unroll
  for (int cc = 0; cc < 2; ++cc)
    #pragma unroll
    for (int rr = 0; rr < 4; ++rr) {
      int row = rbase + lg * 4 + rr;
      int col = cg + cc * 16 + lrow;
      size_t idx = (size_t)row * 128 + col;
      out[idx] = acc[cc][rr] + X1[idx];
    }
}

// ---------------- launch ---------------------------------------------------
extern "C" void kernel_launch(void* const* d_in, const int* in_sizes, int n_in,
                              void* d_out, int out_size, void* d_ws, size_t ws_size,
                              hipStream_t stream)
{
  const float* head    = (const float*)d_in[0];
  const float* tail    = (const float*)d_in[1];
  const float* R_q     = (const float*)d_in[2];
  const float* R_k     = (const float*)d_in[3];
  const float* R_v     = (const float*)d_in[4];
  const float* R_W     = (const float*)d_in[5];
  const float* F_q     = (const float*)d_in[6];
  const float* F_k     = (const float*)d_in[7];
  const float* F_v     = (const float*)d_in[8];
  const float* F_W     = (const float*)d_in[9];
  const float* conv_w  = (const float*)d_in[10];
  const float* conv_b  = (const float*)d_in[11];
  const float* bn_w    = (const float*)d_in[12];
  const float* bn_b    = (const float*)d_in[13];
  const float* bn_mean = (const float*)d_in[14];
  const float* bn_var  = (const float*)d_in[15];
  const int*   flagp   = (const int*)d_in[16];
  float* out = (float*)d_out;

  char* ws = (char*)d_ws;
  u16*   qT   = (u16*)(ws + 262144);      // 1 MB   (b,32,L) bf16
  u16*   KQ   = (u16*)(ws + 1310720);     // 2 MB   (b,L,64) bf16, log2e-scaled
  u16*   Vc   = (u16*)(ws + 3407872);     // 2 MB   (b,L,64) bf16
  u16*   pO   = (u16*)(ws + 6553600);     // 8 MB   [b][8][32][L] bf16 partial sums
  float* pl   = (float*)(ws + 14942208);  // 512 KB [b][8][L] partial denominators

  kproj <<<dim3(128, 5), 256, 0, stream>>>(head, tail, R_q, R_k, R_v,
                                           F_q, F_k, F_v, conv_w, conv_b,
                                           bn_w, bn_b, bn_mean, bn_var,
                                           qT, KQ, Vc, flagp);
  kattn <<<1024, 256, 0, stream>>>(qT, KQ, Vc, pO, pl);
  kout  <<<256, 256, 0, stream>>>(pO, pl, R_W, F_W, head, tail, flagp, out);
}

// Round 20
// 54.409 us; speedup vs baseline: 1.3545x; 1.0249x over previous
//
#include <hip/hip_runtime.h>
#include <hip/hip_bf16.h>
#include <stdint.h>

typedef unsigned short u16;
typedef unsigned int u32;
typedef __attribute__((ext_vector_type(8))) short short8;
typedef __attribute__((ext_vector_type(4))) short short4_t;
typedef __attribute__((ext_vector_type(4))) float f32x4;
typedef __attribute__((ext_vector_type(16))) float f32x16;

#define MFMA16(A,B,C) __builtin_amdgcn_mfma_f32_16x16x32_bf16((A),(B),(C),0,0,0)
#define MFMA32(A,B,C) __builtin_amdgcn_mfma_f32_32x32x16_bf16((A),(B),(C),0,0,0)
#define L2E 1.4426950408889634f

__device__ __forceinline__ u16 f2bf(float f) {
  u32 x = __float_as_uint(f);
  u32 r = x + 0x7fffu + ((x >> 16) & 1u);
  return (u16)(r >> 16);
}
__device__ __forceinline__ float bf2f(short v) {
  return __uint_as_float((u32)(u16)v << 16);
}
__device__ __forceinline__ u32 pack_bf2(float a, float b) {
  __hip_bfloat162 h = __float22bfloat162_rn(make_float2(a, b));
  u32 u; __builtin_memcpy(&u, &h, 4); return u;
}
__device__ __forceinline__ short8 mk_frag(u32 w0, u32 w1, u32 w2, u32 w3) {
  union { u32 u[4]; short8 s; } cv;
  cv.u[0] = w0; cv.u[1] = w1; cv.u[2] = w2; cv.u[3] = w3;
  return cv.s;
}

#if __has_builtin(__builtin_amdgcn_permlane32_swap)
__device__ __forceinline__ float half_sum(float x) {
  u32 xu = __float_as_uint(x);
  auto a = __builtin_amdgcn_permlane32_swap(xu, xu, false, false);
  return __uint_as_float(a[0]) + __uint_as_float(a[1]);
}
#else
__device__ __forceinline__ float half_sum(float x) {
  return x + __shfl_xor(x, 32, 64);
}
#endif

// weight-tile swizzle: separates row stripes AND 32-col groups so transpose
// writes hit distinct bank quartets.  Bits 4..7, bijective per row.
__device__ __forceinline__ int wswz(int n) {
  return ((n & 7) ^ ((n >> 5) & 3)) << 4;
}

// In-block transpose of a 128x128 f32 matrix into a swizzled bf16 LDS tile.
__device__ __forceinline__ void transpose_to_lds(const float* __restrict__ Sg,
                                                 char* btc, int tid)
{
  const int kr = (tid >> 2) * 2;
  const int nc = (tid & 3) * 32;
  const float* r0 = Sg + kr * 128 + nc;
  const float* r1 = r0 + 128;
  #pragma unroll
  for (int j4 = 0; j4 < 8; ++j4) {
    float4 a = *reinterpret_cast<const float4*>(r0 + j4 * 4);
    float4 b = *reinterpret_cast<const float4*>(r1 + j4 * 4);
    #pragma unroll
    for (int e = 0; e < 4; ++e) {
      int n = nc + j4 * 4 + e;
      *reinterpret_cast<u32*>(btc + ((n * 256 + kr * 2) ^ wswz(n))) =
          pack_bf2((&a.x)[e], (&b.x)[e]);
    }
  }
}

// ---------------- kernel 1: 5 projections, packed layouts -----------------
// g=0: qT (b,32,L)   g=1: L2E*k1 -> KQ[:, 0:32]   g=3: L2E*alpha*k2 -> KQ[:,32:64]
// g=2: v1 -> Vc[:,0:32]                           g=4: v2 -> Vc[:,32:64]
// g==3 alpha conv is split across all 256 threads (two c-halves, LDS
// partials) instead of a 64-deep serial loop on 128 threads.
__global__ __launch_bounds__(256) void kproj(const float* __restrict__ head,
    const float* __restrict__ tail,
    const float* __restrict__ R_q, const float* __restrict__ R_k,
    const float* __restrict__ R_v, const float* __restrict__ F_q,
    const float* __restrict__ F_k, const float* __restrict__ F_v,
    const float* __restrict__ conv_w, const float* __restrict__ conv_b,
    const float* __restrict__ bn_w, const float* __restrict__ bn_b,
    const float* __restrict__ bn_mean, const float* __restrict__ bn_var,
    u16* __restrict__ qT, u16* __restrict__ KQ,
    u16* __restrict__ Vc, const int* __restrict__ flagp)
{
  __shared__ __align__(16) char bt[32768];
  __shared__ u16 lds_t[128][34];
  __shared__ float s_alpha[128];
  __shared__ float pa0[2][128], pa1[2][128];
  const int flag = *flagp;
  const float* X1 = flag ? head : tail;
  const float* X2 = flag ? tail : head;
  const int bh = blockIdx.x, g = blockIdx.y;
  const int b = bh >> 5, h = bh & 31;
  const float* src = (g < 3) ? X1 : X2;
  const int tid = threadIdx.x, lane = tid & 63, wid = tid >> 6;
  const int lrow = lane & 15, lg = lane >> 4;
  const int rt = wid & 1, cbase = (wid >> 1) * 64;

  {
    const float* s1[5] = {R_q, R_k, R_v, F_k, F_v};
    const float* s0[5] = {F_q, F_k, F_v, R_k, R_v};
    transpose_to_lds(flag ? s1[g] : s0[g], bt, tid);
  }

  if (g == 3) {                          // alpha partials: all 256 threads
    const int w = tid & 127, hf = tid >> 7;
    const float* hp = head + ((size_t)b * 1024 + h) * 128 + w + (size_t)hf * 16 * 4096;
    const float* tp = tail + ((size_t)b * 1024 + h) * 128 + w + (size_t)hf * 16 * 4096;
    float a0 = 0.f, a1 = 0.f;
    #pragma unroll 4
    for (int c = 0; c < 16; ++c) {
      float xh = hp[c * 4096];
      float xt = tp[c * 4096];
      int cc = hf * 16 + c;
      a0 += xh * conv_w[cc]      + xt * conv_w[32 + cc];
      a1 += xh * conv_w[64 + cc] + xt * conv_w[96 + cc];
    }
    pa0[hf][w] = a0;
    pa1[hf][w] = a1;
  }
  __syncthreads();

  if (g == 3 && tid < 128) {             // combine + BN + ReLU + sigmoid
    int w = tid;
    float a0 = pa0[0][w] + pa0[1][w];
    float a1 = pa1[0][w] + pa1[1][w];
    const float eps = 1e-5f;
    a0 += conv_b[0]; a1 += conv_b[1];
    a0 = (a0 - bn_mean[0]) * (bn_w[0] * rsqrtf(bn_var[0] + eps)) + bn_b[0];
    a1 = (a1 - bn_mean[1]) * (bn_w[1] * rsqrtf(bn_var[1] + eps)) + bn_b[1];
    a0 = fmaxf(a0, 0.f); a1 = fmaxf(a1, 0.f);
    float asel = flag ? a0 : a1, aoth = flag ? a1 : a0;
    s_alpha[w] = 1.f / (1.f + __expf(aoth - asel));
  }

  f32x4 acc[4] = {};
  const float* Arow = src + (((size_t)b * 32 + rt * 16 + lrow) * 32 + h) * 128;
  #pragma unroll
  for (int k0 = 0; k0 < 128; k0 += 32) {
    const float* ap = Arow + k0 + lg * 8;
    float4 f0 = *reinterpret_cast<const float4*>(ap);
    float4 f1 = *reinterpret_cast<const float4*>(ap + 4);
    short8 af = mk_frag(pack_bf2(f0.x, f0.y), pack_bf2(f0.z, f0.w),
                        pack_bf2(f1.x, f1.y), pack_bf2(f1.z, f1.w));
    #pragma unroll
    for (int cc = 0; cc < 4; ++cc) {
      int n = cbase + cc * 16 + lrow;
      short8 bf = *reinterpret_cast<const short8*>(
          bt + ((n * 256 + k0 * 2 + lg * 16) ^ wswz(n)));
      acc[cc] = MFMA16(af, bf, acc[cc]);
    }
  }
  if (g == 3) __syncthreads();           // publish s_alpha (block-uniform g)
  #pragma unroll
  for (int cc = 0; cc < 4; ++cc) {
    int n = cbase + cc * 16 + lrow;
    float asc = (g == 1) ? L2E : 1.f;
    if (g == 3) asc = s_alpha[n] * L2E;
    #pragma unroll
    for (int rr = 0; rr < 4; ++rr) {
      int c = rt * 16 + lg * 4 + rr;
      lds_t[n][c] = f2bf(acc[cc][rr] * asc);
    }
  }
  __syncthreads();
  if (g == 0) {
    int c = tid >> 3, w0 = (tid & 7) * 16;
    int tw[8];
    #pragma unroll
    for (int i2 = 0; i2 < 8; ++i2)
      tw[i2] = (int)lds_t[w0 + 2 * i2][c] | ((int)lds_t[w0 + 2 * i2 + 1][c] << 16);
    int4* dst = reinterpret_cast<int4*>(qT + ((size_t)b * 32 + c) * 4096 + h * 128 + w0);
    dst[0] = make_int4(tw[0], tw[1], tw[2], tw[3]);
    dst[1] = make_int4(tw[4], tw[5], tw[6], tw[7]);
  } else if (tid < 128) {
    int w = tid;
    int tw[16];
    #pragma unroll
    for (int i2 = 0; i2 < 16; ++i2)
      tw[i2] = (int)lds_t[w][2 * i2] | ((int)lds_t[w][2 * i2 + 1] << 16);
    u16* base = (g == 2 || g == 4) ? Vc : KQ;
    int coff = (g >= 3) ? 32 : 0;
    int4* dst = reinterpret_cast<int4*>(base + ((size_t)b * 4096 + h * 128 + w) * 64 + coff);
    dst[0] = make_int4(tw[0],  tw[1],  tw[2],  tw[3]);
    dst[1] = make_int4(tw[4],  tw[5],  tw[6],  tw[7]);
    dst[2] = make_int4(tw[8],  tw[9],  tw[10], tw[11]);
    dst[3] = make_int4(tw[12], tw[13], tw[14], tw[15]);
  }
}

// ---------------- kernel 2: flash attention (R15/R12, proven) -------------
__global__ __launch_bounds__(256, 4) void kattn(const u16* __restrict__ qT,
    const u16* __restrict__ KQ, const u16* __restrict__ Vc,
    u16* __restrict__ pO, float* __restrict__ pl)
{
  __shared__ __align__(16) char lds_v[2][8192];
  __shared__ __align__(16) char lds_q[2][4096];
  const int b = blockIdx.y;
  const int i0 = blockIdx.x * 128;
  const int sp = blockIdx.z;
  const int jbase = sp * 512;
  const int tid = threadIdx.x, lane = tid & 63, wid = tid >> 6;
  const int l31 = lane & 31, h = lane >> 5;
  const int iw = i0 + wid * 32;

  const u16* KQb = KQ + (size_t)b * 4096 * 64;
  const u16* Vb  = Vc + (size_t)b * 4096 * 64;
  const u16* qTb = qT + (size_t)b * 32 * 4096;

  short8 bkq[4];
  #pragma unroll
  for (int c = 0; c < 4; ++c)
    bkq[c] = *reinterpret_cast<const short8*>(
        KQb + (size_t)(iw + l31) * 64 + c * 16 + h * 8);

  const int sr = tid >> 3, sx = (tid & 7) * 16;
  const int pr0 = (sr & ~12) | ((sr & 4) << 1) | ((sr & 8) >> 1);

  #pragma unroll
  for (int q = 0; q < 2; ++q) {
    int r = sr + q * 32, gr = pr0 + q * 32;
    int4 v = *reinterpret_cast<const int4*>(
        reinterpret_cast<const char*>(Vb + (size_t)(jbase + gr) * 64) + sx);
    *reinterpret_cast<int4*>(lds_v[0] + r * 128 + (sx ^ ((r & 7) << 4))) = v;
  }
  {
    int4 qv = *reinterpret_cast<const int4*>(
        qTb + (size_t)sr * 4096 + jbase + (tid & 7) * 8);
    *reinterpret_cast<int4*>(lds_q[0] + sr * 128 + (sx ^ ((sr & 7) << 4))) = qv;
  }
  __syncthreads();

  float l_run = 0.f;
  f32x16 accO = {};
  int4 stgV[2], stgQ;

  for (int t = 0; t < 8; ++t) {
    const int buf = t & 1;
    if (t < 7) {
      const u16* Vn = Vb + (size_t)(jbase + (t + 1) * 64) * 64;
      #pragma unroll
      for (int q = 0; q < 2; ++q) {
        int gr = pr0 + q * 32;
        stgV[q] = *reinterpret_cast<const int4*>(
            reinterpret_cast<const char*>(Vn + (size_t)gr * 64) + sx);
      }
      stgQ = *reinterpret_cast<const int4*>(
          qTb + (size_t)sr * 4096 + jbase + (t + 1) * 64 + (tid & 7) * 8);
    }
    f32x16 st[2];
    st[0] = f32x16{}; st[1] = f32x16{};
    __builtin_amdgcn_s_setprio(1);
    #pragma unroll
    for (int jt = 0; jt < 2; ++jt) {
      int vr = jt * 32 + l31;
      #pragma unroll
      for (int c = 0; c < 4; ++c) {
        short8 av = *reinterpret_cast<const short8*>(
            lds_v[buf] + vr * 128 + ((c * 32 + h * 16) ^ ((vr & 7) << 4)));
        st[jt] = MFMA32(av, bkq[c], st[jt]);
      }
    }
    __builtin_amdgcn_s_setprio(0);
    short8 aq[4];
    #pragma unroll
    for (int cc = 0; cc < 4; ++cc)
      aq[cc] = *reinterpret_cast<const short8*>(
          lds_q[buf] + l31 * 128 + ((cc * 32 + h * 16) ^ ((l31 & 7) << 4)));
    #pragma unroll
    for (int jt = 0; jt < 2; ++jt)
      #pragma unroll
      for (int r = 0; r < 16; ++r) {
        float p = exp2f(st[jt][r]);
        st[jt][r] = p;
        l_run += p;
      }
    __builtin_amdgcn_s_setprio(1);
    #pragma unroll
    for (int cc = 0; cc < 4; ++cc) {
      const int jt = cc >> 1, p8 = (cc & 1) * 8;
      short8 bp = mk_frag(pack_bf2(st[jt][p8 + 0], st[jt][p8 + 1]),
                          pack_bf2(st[jt][p8 + 2], st[jt][p8 + 3]),
                          pack_bf2(st[jt][p8 + 4], st[jt][p8 + 5]),
                          pack_bf2(st[jt][p8 + 6], st[jt][p8 + 7]));
      accO = MFMA32(aq[cc], bp, accO);
    }
    __builtin_amdgcn_s_setprio(0);

    if (t < 7) {
      #pragma unroll
      for (int q = 0; q < 2; ++q) {
        int r = sr + q * 32;
        *reinterpret_cast<int4*>(lds_v[buf ^ 1] + r * 128 + (sx ^ ((r & 7) << 4))) = stgV[q];
      }
      *reinterpret_cast<int4*>(lds_q[buf ^ 1] + sr * 128 + (sx ^ ((sr & 7) << 4))) = stgQ;
      __syncthreads();
    }
  }

  const int i = iw + l31;
  u16* pOb = pO + (size_t)((b * 8 + sp) * 32) * 4096;
  #pragma unroll
  for (int r = 0; r < 16; ++r) {
    int c = (r & 3) + 8 * (r >> 2) + 4 * h;
    pOb[(size_t)c * 4096 + i] = f2bf(accO[r]);
  }
  float l = half_sum(l_run);
  if (h == 0) pl[(b * 8 + sp) * 4096 + i] = l;
}

// ---------------- kernel 3: sum partials + final mix + residual -----------
__global__ __launch_bounds__(256) void kout(const u16* __restrict__ pO,
    const float* __restrict__ pl,
    const float* __restrict__ R_W, const float* __restrict__ F_W,
    const float* __restrict__ head, const float* __restrict__ tail,
    const int* __restrict__ flagp, float* __restrict__ out)
{
  __shared__ __align__(16) char btW[32768];
  __shared__ u16 ylds[16][136];
  const int flag = *flagp;
  const float* X1 = flag ? head : tail;
  const int tid = threadIdx.x;
  const int b = blockIdx.x >> 6, c = (blockIdx.x >> 1) & 31, hh = blockIdx.x & 1;
  const int rbase = b * 1024 + c * 32 + hh * 16;
  const int ioff = hh * 2048 + tid * 8;

  transpose_to_lds(flag ? R_W : F_W, btW, tid);

  #pragma unroll
  for (int iq = 0; iq < 2; ++iq) {
    float4 L4 = {0.f, 0.f, 0.f, 0.f}, y4 = {0.f, 0.f, 0.f, 0.f};
    #pragma unroll
    for (int sp = 0; sp < 8; ++sp) {
      float4 l4 = *reinterpret_cast<const float4*>(
          pl + (size_t)((b * 8 + sp) * 4096) + ioff + iq * 4);
      L4.x += l4.x; L4.y += l4.y; L4.z += l4.z; L4.w += l4.w;
      short4_t o4 = *reinterpret_cast<const short4_t*>(
          pO + (size_t)(((b * 8 + sp) * 32 + c)) * 4096 + ioff + iq * 4);
      y4.x += bf2f(o4[0]); y4.y += bf2f(o4[1]);
      y4.z += bf2f(o4[2]); y4.w += bf2f(o4[3]);
    }
    y4.x /= L4.x; y4.y /= L4.y; y4.z /= L4.z; y4.w /= L4.w;
    uint2 pk2;
    pk2.x = pack_bf2(y4.x, y4.y);
    pk2.y = pack_bf2(y4.z, y4.w);
    *reinterpret_cast<uint2*>(&ylds[tid >> 4][(tid & 15) * 8 + iq * 4]) = pk2;
  }
  __syncthreads();

  const int lane = tid & 63, wid = tid >> 6;
  const int lrow = lane & 15, lg = lane >> 4;
  const int cg = wid * 32;
  f32x4 acc[2] = {};
  #pragma unroll
  for (int k0 = 0; k0 < 128; k0 += 32) {
    short8 af = *reinterpret_cast<const short8*>(&ylds[lrow][k0 + lg * 8]);
    #pragma unroll
    for (int cc = 0; cc < 2; ++cc) {
      int n = cg + cc * 16 + lrow;
      short8 bf = *reinterpret_cast<const short8*>(
          btW + ((n * 256 + k0 * 2 + lg * 16) ^ wswz(n)));
      acc[cc] = MFMA16(af, bf, acc[cc]);
    }
  }
  #pragma unroll
  for (int cc = 0; cc < 2; ++cc)
    #pragma unroll
    for (int rr = 0; rr < 4; ++rr) {
      int row = rbase + lg * 4 + rr;
      int col = cg + cc * 16 + lrow;
      size_t idx = (size_t)row * 128 + col;
      out[idx] = acc[cc][rr] + X1[idx];
    }
}

// ---------------- launch ---------------------------------------------------
extern "C" void kernel_launch(void* const* d_in, const int* in_sizes, int n_in,
                              void* d_out, int out_size, void* d_ws, size_t ws_size,
                              hipStream_t stream)
{
  const float* head    = (const float*)d_in[0];
  const float* tail    = (const float*)d_in[1];
  const float* R_q     = (const float*)d_in[2];
  const float* R_k     = (const float*)d_in[3];
  const float* R_v     = (const float*)d_in[4];
  const float* R_W     = (const float*)d_in[5];
  const float* F_q     = (const float*)d_in[6];
  const float* F_k     = (const float*)d_in[7];
  const float* F_v     = (const float*)d_in[8];
  const float* F_W     = (const float*)d_in[9];
  const float* conv_w  = (const float*)d_in[10];
  const float* conv_b  = (const float*)d_in[11];
  const float* bn_w    = (const float*)d_in[12];
  const float* bn_b    = (const float*)d_in[13];
  const float* bn_mean = (const float*)d_in[14];
  const float* bn_var  = (const float*)d_in[15];
  const int*   flagp   = (const int*)d_in[16];
  float* out = (float*)d_out;

  char* ws = (char*)d_ws;
  u16*   qT   = (u16*)(ws + 262144);      // 1 MB   (b,32,L) bf16
  u16*   KQ   = (u16*)(ws + 1310720);     // 2 MB   (b,L,64) bf16, log2e-scaled
  u16*   Vc   = (u16*)(ws + 3407872);     // 2 MB   (b,L,64) bf16
  u16*   pO   = (u16*)(ws + 6553600);     // 8 MB   [b][8][32][L] bf16 partial sums
  float* pl   = (float*)(ws + 14942208);  // 512 KB [b][8][L] partial denominators

  kproj <<<dim3(128, 5), 256, 0, stream>>>(head, tail, R_q, R_k, R_v,
                                           F_q, F_k, F_v, conv_w, conv_b,
                                           bn_w, bn_b, bn_mean, bn_var,
                                           qT, KQ, Vc, flagp);
  kattn <<<dim3(32, 4, 8), 256, 0, stream>>>(qT, KQ, Vc, pO, pl);
  kout  <<<256, 256, 0, stream>>>(pO, pl, R_W, F_W, head, tail, flagp, out);
}